// Round 14
// baseline (2898.576 us; speedup 1.0000x reference)
//
#include <hip/hip_runtime.h>

// LSTMFeatureExtractor: 2-layer LSTM (H=128) over B=512, T=512, + a*relu(a) head.
// Round 14 = round-12 (best, 806us) + ONE change: S1 no longer stages the h0
// chunk into LDS. Its xf B-fragments are read DIRECTLY from h0r (global,
// L2-resident) via a 2-step register prefetch (xf2[2][4]) — removes the
// per-chunk staging copy + barrier from the limiter stage's critical path.
// fs1 credit moves to chunk end (reads span the chunk; ring depth 4 -> S0
// chunk c waits S1 done with c-4 = exactly when slot(c) frees). P0/S0 verbatim.

typedef _Float16 half8  __attribute__((ext_vector_type(8)));
typedef _Float16 half4_ __attribute__((ext_vector_type(4)));
typedef float    f32x4  __attribute__((ext_vector_type(4)));

#define H_    128
#define T_    512
#define B_    512
#define BCH   16
#define NBG   32
#define NCH   64                  // 8-step chunks
#define KPAD  136
#define RS    4                   // seed ring depth
#define RH    4                   // h0 ring depth
#define SEEDSLOT (8 * 4 * 512 * 4)    // halves per (bg,slot): 65536 (128KB)
#define H0SLOT   (8 * 16 * 128)       // halves per (bg,slot): 16384 (32KB)

#define LOG2E 1.44269504089f

__device__ __forceinline__ float sigm_(float x) {
    return __builtin_amdgcn_rcpf(1.f + __builtin_amdgcn_exp2f(-LOG2E * x));
}
__device__ __forceinline__ float tanh_(float x) {
    return 1.f - 2.f * __builtin_amdgcn_rcpf(1.f + __builtin_amdgcn_exp2f((2.f * LOG2E) * x));
}
__device__ __forceinline__ void lds_barrier() {
    __builtin_amdgcn_sched_barrier(0);
    asm volatile("s_waitcnt lgkmcnt(0)" ::: "memory");
    __builtin_amdgcn_sched_barrier(0);
    __builtin_amdgcn_s_barrier();
    __builtin_amdgcn_sched_barrier(0);
}
__device__ __forceinline__ void fwait(const int* p, int tgt) {
    while (__hip_atomic_load(p, __ATOMIC_ACQUIRE, __HIP_MEMORY_SCOPE_AGENT) < tgt)
        __builtin_amdgcn_s_sleep(2);
}
__device__ __forceinline__ void frel(int* p, int v) {
    __hip_atomic_store(p, v, __ATOMIC_RELEASE, __HIP_MEMORY_SCOPE_AGENT);
}
__device__ __forceinline__ f32x4 cvt4(half4_ h) {
    return f32x4{(float)h[0], (float)h[1], (float)h[2], (float)h[3]};
}
__device__ __forceinline__ half4_ cvh4(f32x4 v) {
    return half4_{(_Float16)v[0], (_Float16)v[1], (_Float16)v[2], (_Float16)v[3]};
}

#define MFMA16(A, Bv, C) __builtin_amdgcn_mfma_f32_16x16x32_f16((A), (Bv), (C), 0, 0, 0)

__global__ void __launch_bounds__(512)
lstm3(const float* __restrict__ y,
      const float* __restrict__ Wih0, const float* __restrict__ Whh0,
      const float* __restrict__ bih0, const float* __restrict__ bhh0,
      const float* __restrict__ Wih1, const float* __restrict__ Whh1,
      const float* __restrict__ bih1, const float* __restrict__ bhh1,
      const float* __restrict__ Wa,  const float* __restrict__ ba,
      _Float16* __restrict__ seeds, _Float16* __restrict__ h0r,
      int* __restrict__ flags, float* __restrict__ out)
{
    __shared__ _Float16 xbuf[8][16][KPAD];   // P0 staging only
    __shared__ _Float16 hbuf[2][16][KPAD];   // S0/S1 h state

    const int tid = threadIdx.x;
    const int w   = tid >> 6;
    const int l   = tid & 63;
    const int g   = l >> 4;
    const int cl  = l & 15;
    const int role = blockIdx.x % 3;     // 0=P0 1=S0 2=S1
    const int bg   = blockIdx.x / 3;
    const int b0   = bg * BCH;

    int* fg0 = flags;        // P0 -> S0: seeds chunk ready
    int* fs0 = flags + 32;   // S0 -> P0: seed slot credit
    int* fh0 = flags + 64;   // S0 -> S1: h0 chunk ready
    int* fs1 = flags + 96;   // S1 -> S0: h0 slot credit (released at chunk END)

    { // zero hbuf (initial h state for S roles)
        int* q = (int*)&hbuf[0][0][0];
        for (int i = tid; i < (int)(sizeof(hbuf) / 4); i += 512) q[i] = 0;
    }

    if (role == 0) {
        // ====================== P0: layer-0 input projection ======================
        half8 wf[4][4];
        #pragma unroll
        for (int gt = 0; gt < 4; ++gt) {
            const int grow = gt * 128 + w * 16 + cl;
            #pragma unroll
            for (int kt = 0; kt < 4; ++kt) {
                const float* pa = Wih0 + grow * H_ + kt * 32 + g * 8;
                f32x4 a0 = *(const f32x4*)(pa);
                f32x4 a1 = *(const f32x4*)(pa + 4);
                half8 fa;
                #pragma unroll
                for (int e = 0; e < 4; ++e) { fa[e] = (_Float16)a0[e]; fa[e + 4] = (_Float16)a1[e]; }
                wf[gt][kt] = fa;
            }
        }
        f32x4 bias[4];
        #pragma unroll
        for (int gt = 0; gt < 4; ++gt)
            #pragma unroll
            for (int r = 0; r < 4; ++r) {
                const int R = gt * 128 + w * 16 + g * 4 + r;
                bias[gt][r] = bih0[R] + bhh0[R];
            }
        __syncthreads();

        for (int c = 0; c < NCH; ++c) {
            if (tid == 0 && c >= RS) fwait(&fs0[bg], c - (RS - 1));
            __syncthreads();

            // stage y[b][k][c*8..+8) -> xbuf (f16)
            #pragma unroll
            for (int rr = 0; rr < 4; ++rr) {
                const int q = tid + rr * 512;
                const int b = q >> 7, k = q & 127;
                const float* src = y + ((size_t)((b0 + b) * H_ + k)) * T_ + c * 8;
                f32x4 v0 = *(const f32x4*)(src);
                f32x4 v1 = *(const f32x4*)(src + 4);
                #pragma unroll
                for (int e = 0; e < 4; ++e) {
                    xbuf[e][b][k]     = (_Float16)v0[e];
                    xbuf[e + 4][b][k] = (_Float16)v1[e];
                }
            }
            lds_barrier();

            _Float16* sb = seeds + (size_t)(bg * RS + (c & (RS - 1))) * SEEDSLOT;
            for (int s = 0; s < 8; ++s) {
                half8 xf[4];
                #pragma unroll
                for (int kt = 0; kt < 4; ++kt)
                    xf[kt] = *(const half8*)&xbuf[s][cl][kt * 32 + g * 8];
                #pragma unroll
                for (int gt = 0; gt < 4; ++gt) {
                    f32x4 acc = bias[gt];
                    #pragma unroll
                    for (int kt = 0; kt < 4; ++kt)
                        acc = MFMA16(wf[gt][kt], xf[kt], acc);
                    // per-consumer-thread layout: [(s*4+gt)*512 + tid]*4 halves
                    *(half4_*)(sb + ((size_t)(s * 4 + gt) * 512 + tid) * 4) = cvh4(acc);
                }
            }
            __syncthreads();                 // drain seed stores (vmcnt)
            if (tid == 0) frel(&fg0[bg], c + 1);
        }
    } else if (role == 1) {
        // ====================== S0: light recurrence, layer 0 ======================
        half8 whh[4][4];
        #pragma unroll
        for (int gt = 0; gt < 4; ++gt) {
            const int grow = gt * 128 + w * 16 + cl;
            #pragma unroll
            for (int kt = 0; kt < 4; ++kt) {
                const float* pb = Whh0 + grow * H_ + kt * 32 + g * 8;
                f32x4 c0 = *(const f32x4*)(pb);
                f32x4 c1 = *(const f32x4*)(pb + 4);
                half8 fb;
                #pragma unroll
                for (int e = 0; e < 4; ++e) { fb[e] = (_Float16)c0[e]; fb[e + 4] = (_Float16)c1[e]; }
                whh[gt][kt] = fb;
            }
        }
        float cst[4] = {0.f, 0.f, 0.f, 0.f};
        __syncthreads();

        for (int c = 0; c < NCH; ++c) {
            if (tid == 0) {
                fwait(&fg0[bg], c + 1);                       // seeds ready
                if (c >= RH) fwait(&fs1[bg], c - (RH - 1));   // h0 slot free
            }
            __syncthreads();

            const _Float16* sb = seeds + (size_t)(bg * RS + (c & (RS - 1))) * SEEDSLOT
                               + (size_t)tid * 4;
            _Float16* hb = h0r + (size_t)(bg * RH + (c & (RH - 1))) * H0SLOT;

            half4_ sd[2][4];
            #pragma unroll
            for (int gt = 0; gt < 4; ++gt)
                sd[0][gt] = *(const half4_*)(sb + (size_t)(0 * 4 + gt) * 2048);
            #pragma unroll
            for (int gt = 0; gt < 4; ++gt)
                sd[1][gt] = *(const half4_*)(sb + (size_t)(1 * 4 + gt) * 2048);

            #pragma unroll
            for (int s = 0; s < 8; ++s) {
                const int rd = (s ^ 1) & 1;
                const int wr = s & 1;

                half8 hf[4];
                #pragma unroll
                for (int kt = 0; kt < 4; ++kt)
                    hf[kt] = *(const half8*)&hbuf[rd][cl][kt * 32 + g * 8];

                f32x4 a0 = cvt4(sd[s & 1][0]);
                f32x4 a1 = cvt4(sd[s & 1][1]);
                f32x4 a2 = cvt4(sd[s & 1][2]);
                f32x4 a3 = cvt4(sd[s & 1][3]);
                if (s + 2 < 8) {
                    #pragma unroll
                    for (int gt = 0; gt < 4; ++gt)
                        sd[s & 1][gt] =
                            *(const half4_*)(sb + (size_t)((s + 2) * 4 + gt) * 2048);
                }

                #pragma unroll
                for (int kt = 0; kt < 4; ++kt) {
                    a0 = MFMA16(whh[0][kt], hf[kt], a0);
                    a1 = MFMA16(whh[1][kt], hf[kt], a1);
                    a2 = MFMA16(whh[2][kt], hf[kt], a2);
                    a3 = MFMA16(whh[3][kt], hf[kt], a3);
                }

                half4_ h4;
                #pragma unroll
                for (int r = 0; r < 4; ++r) {
                    const float is  = sigm_(a0[r]);
                    const float fs  = sigm_(a1[r]);
                    const float gt_ = tanh_(a2[r]);
                    const float os  = sigm_(a3[r]);
                    cst[r] = fs * cst[r] + is * gt_;
                    h4[r] = (_Float16)(os * tanh_(cst[r]));
                }
                const int u0 = w * 16 + g * 4;
                *(half4_*)&hbuf[wr][cl][u0] = h4;
                *(half4_*)(hb + (s * 16 + cl) * 128 + u0) = h4;

                if (s < 7) {
                    lds_barrier();
                } else {
                    __syncthreads();            // drain h0 stores + seed loads
                    if (tid == 0) {
                        frel(&fh0[bg], c + 1);  // h0 chunk ready for S1
                        frel(&fs0[bg], c + 1);  // seed slot free for P0
                    }
                }
            }
        }
    } else {
        // ========== S1: layer-1 recurrence + head (direct-global xf) ==========
        half8 wihf[4][4], whhf[4][4];
        #pragma unroll
        for (int gt = 0; gt < 4; ++gt) {
            const int grow = gt * 128 + w * 16 + cl;
            #pragma unroll
            for (int kt = 0; kt < 4; ++kt) {
                const float* pa = Wih1 + grow * H_ + kt * 32 + g * 8;
                const float* pb = Whh1 + grow * H_ + kt * 32 + g * 8;
                f32x4 a0 = *(const f32x4*)(pa);
                f32x4 a1 = *(const f32x4*)(pa + 4);
                f32x4 c0 = *(const f32x4*)(pb);
                f32x4 c1 = *(const f32x4*)(pb + 4);
                half8 fa, fb;
                #pragma unroll
                for (int e = 0; e < 4; ++e) {
                    fa[e] = (_Float16)a0[e]; fa[e + 4] = (_Float16)a1[e];
                    fb[e] = (_Float16)c0[e]; fb[e + 4] = (_Float16)c1[e];
                }
                wihf[gt][kt] = fa; whhf[gt][kt] = fb;
            }
        }
        f32x4 bias[4];
        #pragma unroll
        for (int gt = 0; gt < 4; ++gt)
            #pragma unroll
            for (int r = 0; r < 4; ++r) {
                const int R = gt * 128 + w * 16 + g * 4 + r;
                bias[gt][r] = bih1[R] + bhh1[R];
            }
        half8 waf[4];
        f32x4 ba4  = {0.f, 0.f, 0.f, 0.f};
        f32x4 oacc = {0.f, 0.f, 0.f, 0.f};
        #pragma unroll
        for (int kt = 0; kt < 4; ++kt) {
            const float* p = Wa + (w * 16 + cl) * H_ + kt * 32 + g * 8;
            f32x4 a0 = *(const f32x4*)(p);
            f32x4 a1 = *(const f32x4*)(p + 4);
            half8 f;
            #pragma unroll
            for (int e = 0; e < 4; ++e) { f[e] = (_Float16)a0[e]; f[e + 4] = (_Float16)a1[e]; }
            waf[kt] = f;
        }
        #pragma unroll
        for (int r = 0; r < 4; ++r) ba4[r] = ba[w * 16 + g * 4 + r];

        float cst[4] = {0.f, 0.f, 0.f, 0.f};
        __syncthreads();

        for (int c = 0; c < NCH; ++c) {
            if (tid == 0) fwait(&fh0[bg], c + 1);
            __syncthreads();

            // per-thread xf base in h0r slot: row cl, halves g*8 + kt*32
            const _Float16* hbp = h0r + (size_t)(bg * RH + (c & (RH - 1))) * H0SLOT
                                + cl * 128 + g * 8;
            half8 xf2[2][4];
            #pragma unroll
            for (int kt = 0; kt < 4; ++kt)
                xf2[0][kt] = *(const half8*)(hbp + 0 * 2048 + kt * 32);
            #pragma unroll
            for (int kt = 0; kt < 4; ++kt)
                xf2[1][kt] = *(const half8*)(hbp + 1 * 2048 + kt * 32);

            #pragma unroll
            for (int s = 0; s < 8; ++s) {
                const int t  = c * 8 + s;
                const int rd = (s ^ 1) & 1;
                const int wr = s & 1;

                half8 hf[4], xfu[4];
                #pragma unroll
                for (int kt = 0; kt < 4; ++kt) {
                    xfu[kt] = xf2[s & 1][kt];
                    hf[kt]  = *(const half8*)&hbuf[rd][cl][kt * 32 + g * 8];
                }
                if (s + 2 < 8) {   // prefetch xf for step s+2 (off-chain)
                    #pragma unroll
                    for (int kt = 0; kt < 4; ++kt)
                        xf2[s & 1][kt] =
                            *(const half8*)(hbp + (size_t)(s + 2) * 2048 + kt * 32);
                }

                f32x4 ai0 = bias[0], ai1 = bias[1], ai2 = bias[2], ai3 = bias[3];
                f32x4 ah0 = {0,0,0,0}, ah1 = {0,0,0,0}, ah2 = {0,0,0,0}, ah3 = {0,0,0,0};
                #pragma unroll
                for (int kt = 0; kt < 4; ++kt) {
                    ai0 = MFMA16(wihf[0][kt], xfu[kt], ai0);
                    ai1 = MFMA16(wihf[1][kt], xfu[kt], ai1);
                    ai2 = MFMA16(wihf[2][kt], xfu[kt], ai2);
                    ai3 = MFMA16(wihf[3][kt], xfu[kt], ai3);
                    ah0 = MFMA16(whhf[0][kt], hf[kt], ah0);
                    ah1 = MFMA16(whhf[1][kt], hf[kt], ah1);
                    ah2 = MFMA16(whhf[2][kt], hf[kt], ah2);
                    ah3 = MFMA16(whhf[3][kt], hf[kt], ah3);
                }

                if (t > 0) {   // head term for h1(t-1)
                    f32x4 aacc = ba4;
                    #pragma unroll
                    for (int kt = 0; kt < 4; ++kt) aacc = MFMA16(waf[kt], hf[kt], aacc);
                    #pragma unroll
                    for (int r = 0; r < 4; ++r) {
                        const float a = aacc[r];
                        oacc[r] += a * fmaxf(a, 0.f);
                    }
                }

                half4_ h4;
                #pragma unroll
                for (int r = 0; r < 4; ++r) {
                    const float i_ = ai0[r] + ah0[r];
                    const float f_ = ai1[r] + ah1[r];
                    const float g_ = ai2[r] + ah2[r];
                    const float o_ = ai3[r] + ah3[r];
                    const float is = sigm_(i_);
                    const float fs = sigm_(f_);
                    const float gt_ = tanh_(g_);
                    const float os = sigm_(o_);
                    cst[r] = fs * cst[r] + is * gt_;
                    h4[r] = (_Float16)(os * tanh_(cst[r]));
                }
                const int u0 = w * 16 + g * 4;
                *(half4_*)&hbuf[wr][cl][u0] = h4;

                if (s < 7) {
                    lds_barrier();
                } else {
                    __syncthreads();               // h0r reads of slot c retired
                    if (tid == 0) frel(&fs1[bg], c + 1);   // slot free for S0
                }
            }
        }

        // final head term for h1(T-1) in hbuf[1]
        f32x4 aacc = ba4;
        #pragma unroll
        for (int kt = 0; kt < 4; ++kt) {
            const half8 hfv = *(const half8*)&hbuf[1][cl][kt * 32 + g * 8];
            aacc = MFMA16(waf[kt], hfv, aacc);
        }
        #pragma unroll
        for (int r = 0; r < 4; ++r) {
            const float a = aacc[r];
            oacc[r] += a * fmaxf(a, 0.f);
        }
        *(f32x4*)&out[(size_t)(b0 + cl) * H_ + w * 16 + g * 4] = oacc;
    }
}

extern "C" void kernel_launch(void* const* d_in, const int* in_sizes, int n_in,
                              void* d_out, int out_size, void* d_ws, size_t ws_size,
                              hipStream_t stream) {
    const float* y    = (const float*)d_in[0];
    const float* Wih0 = (const float*)d_in[1];
    const float* Whh0 = (const float*)d_in[2];
    const float* bih0 = (const float*)d_in[3];
    const float* bhh0 = (const float*)d_in[4];
    const float* Wih1 = (const float*)d_in[5];
    const float* Whh1 = (const float*)d_in[6];
    const float* bih1 = (const float*)d_in[7];
    const float* bhh1 = (const float*)d_in[8];
    const float* Wa   = (const float*)d_in[9];
    const float* ba   = (const float*)d_in[10];
    float* out = (float*)d_out;

    const size_t SEED_BYTES = (size_t)NBG * RS * SEEDSLOT * 2;   // 16 MiB
    const size_t H0_BYTES   = (size_t)NBG * RH * H0SLOT * 2;     // 4 MiB
    char* p = (char*)d_ws;
    _Float16* seeds = (_Float16*)p;             p += SEED_BYTES;
    _Float16* h0r   = (_Float16*)p;             p += H0_BYTES;
    int*      flags = (int*)p;

    hipMemsetAsync(flags, 0, 512, stream);
    lstm3<<<3 * NBG, 512, 0, stream>>>(y, Wih0, Whh0, bih0, bhh0,
                                       Wih1, Whh1, bih1, bhh1, Wa, ba,
                                       seeds, h0r, flags, out);
}

// Round 15
// 1128.414 us; speedup vs baseline: 2.5687x; 2.5687x over previous
//
#include <hip/hip_runtime.h>

// LSTMFeatureExtractor: 2-layer LSTM (H=128) over B=512, T=512, + a*relu(a) head.
// Round 15 = round-12 pipeline, but the layer-1 input projection moves to P0
// (the THROUGHPUT stage, which has ~3x beat slack) instead of S0 (r13's mistake)
// or scattered-global S1 reads (r14's mistake).
//  P0: per beat c: [A] wait h0(c) from S0, stage it (coalesced), compute
//      seeds1(c) = f16(bias1 + Wih1*h0) -> ring, release fg1/fp0;
//      [B] compute seeds0(c+4) from y (prologue fills slots 0..3).
//  S0: light chain: 16 hh-MFMAs from seeds0 + nonlin + h0-ring store. (r12 verbatim)
//  S1: light chain: 16 hh + 4 head MFMAs from seeds1 (register-prefetched,
//      per-thread-contiguous — the r12-proven pattern), nonlin, out.
// Rings all depth 4, lag audited: P0(c) <- S0(c) <- P0(c-4); P0(c) <- S1(c-4)
// <- P0(c-4). Monotone, no cycle. 96 blocks co-resident.

typedef _Float16 half8  __attribute__((ext_vector_type(8)));
typedef _Float16 half4_ __attribute__((ext_vector_type(4)));
typedef float    f32x4  __attribute__((ext_vector_type(4)));

#define H_    128
#define T_    512
#define B_    512
#define BCH   16
#define NBG   32
#define NCH   64                  // 8-step chunks
#define KPAD  136
#define RS    4                   // ring depths (seeds0, seeds1, h0)
#define SEEDSLOT (8 * 4 * 512 * 4)    // halves per (bg,slot): 65536 (128KB)
#define H0SLOT   (8 * 16 * 128)       // halves per (bg,slot): 16384 (32KB)

#define LOG2E 1.44269504089f

__device__ __forceinline__ float sigm_(float x) {
    return __builtin_amdgcn_rcpf(1.f + __builtin_amdgcn_exp2f(-LOG2E * x));
}
__device__ __forceinline__ float tanh_(float x) {
    return 1.f - 2.f * __builtin_amdgcn_rcpf(1.f + __builtin_amdgcn_exp2f((2.f * LOG2E) * x));
}
__device__ __forceinline__ void lds_barrier() {
    __builtin_amdgcn_sched_barrier(0);
    asm volatile("s_waitcnt lgkmcnt(0)" ::: "memory");
    __builtin_amdgcn_sched_barrier(0);
    __builtin_amdgcn_s_barrier();
    __builtin_amdgcn_sched_barrier(0);
}
__device__ __forceinline__ void fwait(const int* p, int tgt) {
    while (__hip_atomic_load(p, __ATOMIC_ACQUIRE, __HIP_MEMORY_SCOPE_AGENT) < tgt)
        __builtin_amdgcn_s_sleep(2);
}
__device__ __forceinline__ void frel(int* p, int v) {
    __hip_atomic_store(p, v, __ATOMIC_RELEASE, __HIP_MEMORY_SCOPE_AGENT);
}
__device__ __forceinline__ f32x4 cvt4(half4_ h) {
    return f32x4{(float)h[0], (float)h[1], (float)h[2], (float)h[3]};
}
__device__ __forceinline__ half4_ cvh4(f32x4 v) {
    return half4_{(_Float16)v[0], (_Float16)v[1], (_Float16)v[2], (_Float16)v[3]};
}

#define MFMA16(A, Bv, C) __builtin_amdgcn_mfma_f32_16x16x32_f16((A), (Bv), (C), 0, 0, 0)

__global__ void __launch_bounds__(512)
lstm3(const float* __restrict__ y,
      const float* __restrict__ Wih0, const float* __restrict__ Whh0,
      const float* __restrict__ bih0, const float* __restrict__ bhh0,
      const float* __restrict__ Wih1, const float* __restrict__ Whh1,
      const float* __restrict__ bih1, const float* __restrict__ bhh1,
      const float* __restrict__ Wa,  const float* __restrict__ ba,
      _Float16* __restrict__ seeds0, _Float16* __restrict__ seeds1,
      _Float16* __restrict__ h0r,
      int* __restrict__ flags, float* __restrict__ out)
{
    __shared__ _Float16 xbuf[8][16][KPAD];   // P0 staging (y and h0, reused)
    __shared__ _Float16 hbuf[2][16][KPAD];   // S0/S1 h state

    const int tid = threadIdx.x;
    const int w   = tid >> 6;
    const int l   = tid & 63;
    const int g   = l >> 4;
    const int cl  = l & 15;
    const int role = blockIdx.x % 3;     // 0=P0 1=S0 2=S1
    const int bg   = blockIdx.x / 3;
    const int b0   = bg * BCH;

    int* fg0 = flags;         // P0 -> S0: seeds0 chunk ready
    int* fs0 = flags + 32;    // S0 -> P0: seeds0 slot credit
    int* fh0 = flags + 64;    // S0 -> P0: h0 chunk ready
    int* fp0 = flags + 96;    // P0 -> S0: h0 slot credit
    int* fg1 = flags + 128;   // P0 -> S1: seeds1 chunk ready
    int* fs1 = flags + 160;   // S1 -> P0: seeds1 slot credit

    { // zero hbuf (initial h state for S roles)
        int* q = (int*)&hbuf[0][0][0];
        for (int i = tid; i < (int)(sizeof(hbuf) / 4); i += 512) q[i] = 0;
    }

    if (role == 0) {
        // =============== P0: both input projections (throughput stage) ===============
        half8 wf0[4][4], wf1[4][4];
        #pragma unroll
        for (int gt = 0; gt < 4; ++gt) {
            const int grow = gt * 128 + w * 16 + cl;
            #pragma unroll
            for (int kt = 0; kt < 4; ++kt) {
                const float* pa = Wih0 + grow * H_ + kt * 32 + g * 8;
                const float* pb = Wih1 + grow * H_ + kt * 32 + g * 8;
                f32x4 a0 = *(const f32x4*)(pa);
                f32x4 a1 = *(const f32x4*)(pa + 4);
                f32x4 c0 = *(const f32x4*)(pb);
                f32x4 c1 = *(const f32x4*)(pb + 4);
                half8 fa, fb;
                #pragma unroll
                for (int e = 0; e < 4; ++e) {
                    fa[e] = (_Float16)a0[e]; fa[e + 4] = (_Float16)a1[e];
                    fb[e] = (_Float16)c0[e]; fb[e + 4] = (_Float16)c1[e];
                }
                wf0[gt][kt] = fa; wf1[gt][kt] = fb;
            }
        }
        f32x4 bias0[4], bias1[4];
        #pragma unroll
        for (int gt = 0; gt < 4; ++gt)
            #pragma unroll
            for (int r = 0; r < 4; ++r) {
                const int R = gt * 128 + w * 16 + g * 4 + r;
                bias0[gt][r] = bih0[R] + bhh0[R];
                bias1[gt][r] = bih1[R] + bhh1[R];
            }
        __syncthreads();

        auto stage_y = [&](int ca) {
            #pragma unroll
            for (int rr = 0; rr < 4; ++rr) {
                const int q = tid + rr * 512;
                const int b = q >> 7, k = q & 127;
                const float* src = y + ((size_t)((b0 + b) * H_ + k)) * T_ + ca * 8;
                f32x4 v0 = *(const f32x4*)(src);
                f32x4 v1 = *(const f32x4*)(src + 4);
                #pragma unroll
                for (int e = 0; e < 4; ++e) {
                    xbuf[e][b][k]     = (_Float16)v0[e];
                    xbuf[e + 4][b][k] = (_Float16)v1[e];
                }
            }
        };
        auto gemm_seeds = [&](_Float16* sb, const half8 (&wf)[4][4], const f32x4 (&bs)[4]) {
            for (int s = 0; s < 8; ++s) {
                half8 xf[4];
                #pragma unroll
                for (int kt = 0; kt < 4; ++kt)
                    xf[kt] = *(const half8*)&xbuf[s][cl][kt * 32 + g * 8];
                #pragma unroll
                for (int gt = 0; gt < 4; ++gt) {
                    f32x4 acc = bs[gt];
                    #pragma unroll
                    for (int kt = 0; kt < 4; ++kt)
                        acc = MFMA16(wf[gt][kt], xf[kt], acc);
                    *(half4_*)(sb + ((size_t)(s * 4 + gt) * 512 + tid) * 4) = cvh4(acc);
                }
            }
        };

        // prologue: seeds0 slots 0..3
        for (int ca = 0; ca < RS; ++ca) {
            stage_y(ca);
            lds_barrier();
            gemm_seeds(seeds0 + (size_t)(bg * RS + ca) * SEEDSLOT, wf0, bias0);
            __syncthreads();
            if (tid == 0) frel(&fg0[bg], ca + 1);
            lds_barrier();   // xbuf reuse safety
        }

        for (int c = 0; c < NCH; ++c) {
            // [A] seeds1(c) from h0(c)
            if (tid == 0) {
                fwait(&fh0[bg], c + 1);                       // h0(c) ready
                if (c >= RS) fwait(&fs1[bg], c - (RS - 1));   // seeds1 slot free
            }
            __syncthreads();
            {   // stage h0 slot c -> xbuf (coalesced)
                const _Float16* sbh = h0r + (size_t)(bg * RS + (c & (RS - 1))) * H0SLOT;
                const int pq = tid >> 2;
                const int b = pq >> 3, trow = pq & 7;
                const int u0 = (tid & 3) * 32;
                const _Float16* src = sbh + (trow * 16 + b) * 128 + u0;
                #pragma unroll
                for (int e = 0; e < 4; ++e) {
                    half8 v = *(const half8*)(src + e * 8);
                    *(half8*)&xbuf[trow][b][u0 + e * 8] = v;
                }
            }
            lds_barrier();
            gemm_seeds(seeds1 + (size_t)(bg * RS + (c & (RS - 1))) * SEEDSLOT, wf1, bias1);
            __syncthreads();          // drain seeds1 stores + h0 reads
            if (tid == 0) {
                frel(&fg1[bg], c + 1);   // seeds1 ready for S1
                frel(&fp0[bg], c + 1);   // h0 slot free for S0
            }

            // [B] seeds0(c+4) from y
            const int ca = c + RS;
            if (ca < NCH) {
                if (tid == 0) fwait(&fs0[bg], ca - (RS - 1));   // slot free (S0 done c)
                __syncthreads();
                stage_y(ca);
                lds_barrier();
                gemm_seeds(seeds0 + (size_t)(bg * RS + (ca & (RS - 1))) * SEEDSLOT, wf0, bias0);
                __syncthreads();
                if (tid == 0) frel(&fg0[bg], ca + 1);
                lds_barrier();   // xbuf reuse safety
            }
        }
    } else if (role == 1) {
        // ====================== S0: light recurrence, layer 0 ======================
        half8 whh[4][4];
        #pragma unroll
        for (int gt = 0; gt < 4; ++gt) {
            const int grow = gt * 128 + w * 16 + cl;
            #pragma unroll
            for (int kt = 0; kt < 4; ++kt) {
                const float* pb = Whh0 + grow * H_ + kt * 32 + g * 8;
                f32x4 c0 = *(const f32x4*)(pb);
                f32x4 c1 = *(const f32x4*)(pb + 4);
                half8 fb;
                #pragma unroll
                for (int e = 0; e < 4; ++e) { fb[e] = (_Float16)c0[e]; fb[e + 4] = (_Float16)c1[e]; }
                whh[gt][kt] = fb;
            }
        }
        float cst[4] = {0.f, 0.f, 0.f, 0.f};
        __syncthreads();

        for (int c = 0; c < NCH; ++c) {
            if (tid == 0) {
                fwait(&fg0[bg], c + 1);                       // seeds0 ready
                if (c >= RS) fwait(&fp0[bg], c - (RS - 1));   // h0 slot free
            }
            __syncthreads();

            const _Float16* sb = seeds0 + (size_t)(bg * RS + (c & (RS - 1))) * SEEDSLOT
                               + (size_t)tid * 4;
            _Float16* hb = h0r + (size_t)(bg * RS + (c & (RS - 1))) * H0SLOT;

            half4_ sd[2][4];
            #pragma unroll
            for (int gt = 0; gt < 4; ++gt)
                sd[0][gt] = *(const half4_*)(sb + (size_t)(0 * 4 + gt) * 2048);
            #pragma unroll
            for (int gt = 0; gt < 4; ++gt)
                sd[1][gt] = *(const half4_*)(sb + (size_t)(1 * 4 + gt) * 2048);

            #pragma unroll
            for (int s = 0; s < 8; ++s) {
                const int rd = (s ^ 1) & 1;
                const int wr = s & 1;

                half8 hf[4];
                #pragma unroll
                for (int kt = 0; kt < 4; ++kt)
                    hf[kt] = *(const half8*)&hbuf[rd][cl][kt * 32 + g * 8];

                f32x4 a0 = cvt4(sd[s & 1][0]);
                f32x4 a1 = cvt4(sd[s & 1][1]);
                f32x4 a2 = cvt4(sd[s & 1][2]);
                f32x4 a3 = cvt4(sd[s & 1][3]);
                if (s + 2 < 8) {
                    #pragma unroll
                    for (int gt = 0; gt < 4; ++gt)
                        sd[s & 1][gt] =
                            *(const half4_*)(sb + (size_t)((s + 2) * 4 + gt) * 2048);
                }

                #pragma unroll
                for (int kt = 0; kt < 4; ++kt) {
                    a0 = MFMA16(whh[0][kt], hf[kt], a0);
                    a1 = MFMA16(whh[1][kt], hf[kt], a1);
                    a2 = MFMA16(whh[2][kt], hf[kt], a2);
                    a3 = MFMA16(whh[3][kt], hf[kt], a3);
                }

                half4_ h4;
                #pragma unroll
                for (int r = 0; r < 4; ++r) {
                    const float is  = sigm_(a0[r]);
                    const float fs  = sigm_(a1[r]);
                    const float gt_ = tanh_(a2[r]);
                    const float os  = sigm_(a3[r]);
                    cst[r] = fs * cst[r] + is * gt_;
                    h4[r] = (_Float16)(os * tanh_(cst[r]));
                }
                const int u0 = w * 16 + g * 4;
                *(half4_*)&hbuf[wr][cl][u0] = h4;
                *(half4_*)(hb + (s * 16 + cl) * 128 + u0) = h4;

                if (s < 7) {
                    lds_barrier();
                } else {
                    __syncthreads();            // drain h0 stores + seed loads
                    if (tid == 0) {
                        frel(&fh0[bg], c + 1);  // h0 ready for P0
                        frel(&fs0[bg], c + 1);  // seeds0 slot free for P0
                    }
                }
            }
        }
    } else {
        // ============ S1: light layer-1 recurrence + head ============
        half8 whh[4][4];
        #pragma unroll
        for (int gt = 0; gt < 4; ++gt) {
            const int grow = gt * 128 + w * 16 + cl;
            #pragma unroll
            for (int kt = 0; kt < 4; ++kt) {
                const float* pb = Whh1 + grow * H_ + kt * 32 + g * 8;
                f32x4 c0 = *(const f32x4*)(pb);
                f32x4 c1 = *(const f32x4*)(pb + 4);
                half8 fb;
                #pragma unroll
                for (int e = 0; e < 4; ++e) { fb[e] = (_Float16)c0[e]; fb[e + 4] = (_Float16)c1[e]; }
                whh[gt][kt] = fb;
            }
        }
        half8 waf[4];
        f32x4 ba4  = {0.f, 0.f, 0.f, 0.f};
        f32x4 oacc = {0.f, 0.f, 0.f, 0.f};
        #pragma unroll
        for (int kt = 0; kt < 4; ++kt) {
            const float* p = Wa + (w * 16 + cl) * H_ + kt * 32 + g * 8;
            f32x4 a0 = *(const f32x4*)(p);
            f32x4 a1 = *(const f32x4*)(p + 4);
            half8 f;
            #pragma unroll
            for (int e = 0; e < 4; ++e) { f[e] = (_Float16)a0[e]; f[e + 4] = (_Float16)a1[e]; }
            waf[kt] = f;
        }
        #pragma unroll
        for (int r = 0; r < 4; ++r) ba4[r] = ba[w * 16 + g * 4 + r];

        float cst[4] = {0.f, 0.f, 0.f, 0.f};
        __syncthreads();

        for (int c = 0; c < NCH; ++c) {
            if (tid == 0) fwait(&fg1[bg], c + 1);
            __syncthreads();

            const _Float16* sb = seeds1 + (size_t)(bg * RS + (c & (RS - 1))) * SEEDSLOT
                               + (size_t)tid * 4;
            half4_ sd[2][4];
            #pragma unroll
            for (int gt = 0; gt < 4; ++gt)
                sd[0][gt] = *(const half4_*)(sb + (size_t)(0 * 4 + gt) * 2048);
            #pragma unroll
            for (int gt = 0; gt < 4; ++gt)
                sd[1][gt] = *(const half4_*)(sb + (size_t)(1 * 4 + gt) * 2048);

            #pragma unroll
            for (int s = 0; s < 8; ++s) {
                const int t  = c * 8 + s;
                const int rd = (s ^ 1) & 1;
                const int wr = s & 1;

                half8 hf[4];       // h1(t-1)
                #pragma unroll
                for (int kt = 0; kt < 4; ++kt)
                    hf[kt] = *(const half8*)&hbuf[rd][cl][kt * 32 + g * 8];

                f32x4 a0 = cvt4(sd[s & 1][0]);
                f32x4 a1 = cvt4(sd[s & 1][1]);
                f32x4 a2 = cvt4(sd[s & 1][2]);
                f32x4 a3 = cvt4(sd[s & 1][3]);
                if (s + 2 < 8) {
                    #pragma unroll
                    for (int gt = 0; gt < 4; ++gt)
                        sd[s & 1][gt] =
                            *(const half4_*)(sb + (size_t)((s + 2) * 4 + gt) * 2048);
                }
                #pragma unroll
                for (int kt = 0; kt < 4; ++kt) {
                    a0 = MFMA16(whh[0][kt], hf[kt], a0);
                    a1 = MFMA16(whh[1][kt], hf[kt], a1);
                    a2 = MFMA16(whh[2][kt], hf[kt], a2);
                    a3 = MFMA16(whh[3][kt], hf[kt], a3);
                }

                if (t > 0) {     // head term for h1(t-1)
                    f32x4 aacc = ba4;
                    #pragma unroll
                    for (int kt = 0; kt < 4; ++kt) aacc = MFMA16(waf[kt], hf[kt], aacc);
                    #pragma unroll
                    for (int r = 0; r < 4; ++r) {
                        const float a = aacc[r];
                        oacc[r] += a * fmaxf(a, 0.f);
                    }
                }

                half4_ h4;
                #pragma unroll
                for (int r = 0; r < 4; ++r) {
                    const float is  = sigm_(a0[r]);
                    const float fs  = sigm_(a1[r]);
                    const float gt_ = tanh_(a2[r]);
                    const float os  = sigm_(a3[r]);
                    cst[r] = fs * cst[r] + is * gt_;
                    h4[r] = (_Float16)(os * tanh_(cst[r]));
                }
                const int u0 = w * 16 + g * 4;
                *(half4_*)&hbuf[wr][cl][u0] = h4;

                if (s < 7) {
                    lds_barrier();
                } else {
                    __syncthreads();               // seeds1 reads retired
                    if (tid == 0) frel(&fs1[bg], c + 1);
                }
            }
        }

        // final head term for h1(T-1) in hbuf[1]
        f32x4 aacc = ba4;
        #pragma unroll
        for (int kt = 0; kt < 4; ++kt) {
            const half8 hfv = *(const half8*)&hbuf[1][cl][kt * 32 + g * 8];
            aacc = MFMA16(waf[kt], hfv, aacc);
        }
        #pragma unroll
        for (int r = 0; r < 4; ++r) {
            const float a = aacc[r];
            oacc[r] += a * fmaxf(a, 0.f);
        }
        *(f32x4*)&out[(size_t)(b0 + cl) * H_ + w * 16 + g * 4] = oacc;
    }
}

extern "C" void kernel_launch(void* const* d_in, const int* in_sizes, int n_in,
                              void* d_out, int out_size, void* d_ws, size_t ws_size,
                              hipStream_t stream) {
    const float* y    = (const float*)d_in[0];
    const float* Wih0 = (const float*)d_in[1];
    const float* Whh0 = (const float*)d_in[2];
    const float* bih0 = (const float*)d_in[3];
    const float* bhh0 = (const float*)d_in[4];
    const float* Wih1 = (const float*)d_in[5];
    const float* Whh1 = (const float*)d_in[6];
    const float* bih1 = (const float*)d_in[7];
    const float* bhh1 = (const float*)d_in[8];
    const float* Wa   = (const float*)d_in[9];
    const float* ba   = (const float*)d_in[10];
    float* out = (float*)d_out;

    const size_t SEED_BYTES = (size_t)NBG * RS * SEEDSLOT * 2;   // 16 MiB each
    const size_t H0_BYTES   = (size_t)NBG * RS * H0SLOT * 2;     // 4 MiB
    char* p = (char*)d_ws;
    _Float16* seeds0 = (_Float16*)p;            p += SEED_BYTES;
    _Float16* seeds1 = (_Float16*)p;            p += SEED_BYTES;
    _Float16* h0r    = (_Float16*)p;            p += H0_BYTES;
    int*      flags  = (int*)p;

    hipMemsetAsync(flags, 0, 1024, stream);
    lstm3<<<3 * NBG, 512, 0, stream>>>(y, Wih0, Whh0, bih0, bhh0,
                                       Wih1, Whh1, bih1, bhh1, Wa, ba,
                                       seeds0, seeds1, h0r, flags, out);
}

// Round 16
// 1080.506 us; speedup vs baseline: 2.6826x; 1.0443x over previous
//
#include <hip/hip_runtime.h>

// LSTMFeatureExtractor: 2-layer LSTM (H=128) over B=512, T=512, + a*relu(a) head.
// Round 16: 4-role pipeline, 128 blocks x 512 thr (r11's shape, r12's fixes).
//  P0: seeds0 = bias0 + x@Wih0^T      -> 4-deep f16 ring (per-thread order)   [r12 verbatim]
//  S0: light rec-0: 16 hh-MFMAs + nonlin + h0 -> 4-deep ring                  [r12 verbatim]
//  P1: stage h0(c) (coalesced), seeds1 = bias1 + Wih1*h0 -> 4-deep f16 ring
//  S1: light rec-1 + head: 16 hh + 4 head MFMAs, seeds1 reg-prefetched        [r15-S1 verbatim]
// All rings depth 4 (r11's depth-2 rings were its stall source). Flags:
//  fg0 P0->S0 ready | fs0 S0->P0 credit | fh0 S0->P1 ready | fp1 P1->S0 h0 credit
//  fg1 P1->S1 ready | fs1 S1->P1 credit.  Unrolled dep graph is a DAG (lag-4
// back-edges). Stage beats: P0~7k, P1~5k, S0~24k, S1~27k cyc -> S1-limited.

typedef _Float16 half8  __attribute__((ext_vector_type(8)));
typedef _Float16 half4_ __attribute__((ext_vector_type(4)));
typedef float    f32x4  __attribute__((ext_vector_type(4)));

#define H_    128
#define T_    512
#define B_    512
#define BCH   16
#define NBG   32
#define NCH   64                  // 8-step chunks
#define KPAD  136
#define RS    4                   // ALL ring depths
#define SEEDSLOT (8 * 4 * 512 * 4)    // halves per (bg,slot): 65536 (128KB)
#define H0SLOT   (8 * 16 * 128)       // halves per (bg,slot): 16384 (32KB)

#define LOG2E 1.44269504089f

__device__ __forceinline__ float sigm_(float x) {
    return __builtin_amdgcn_rcpf(1.f + __builtin_amdgcn_exp2f(-LOG2E * x));
}
__device__ __forceinline__ float tanh_(float x) {
    return 1.f - 2.f * __builtin_amdgcn_rcpf(1.f + __builtin_amdgcn_exp2f((2.f * LOG2E) * x));
}
__device__ __forceinline__ void lds_barrier() {
    __builtin_amdgcn_sched_barrier(0);
    asm volatile("s_waitcnt lgkmcnt(0)" ::: "memory");
    __builtin_amdgcn_sched_barrier(0);
    __builtin_amdgcn_s_barrier();
    __builtin_amdgcn_sched_barrier(0);
}
__device__ __forceinline__ void fwait(const int* p, int tgt) {
    while (__hip_atomic_load(p, __ATOMIC_ACQUIRE, __HIP_MEMORY_SCOPE_AGENT) < tgt)
        __builtin_amdgcn_s_sleep(2);
}
__device__ __forceinline__ void frel(int* p, int v) {
    __hip_atomic_store(p, v, __ATOMIC_RELEASE, __HIP_MEMORY_SCOPE_AGENT);
}
__device__ __forceinline__ f32x4 cvt4(half4_ h) {
    return f32x4{(float)h[0], (float)h[1], (float)h[2], (float)h[3]};
}
__device__ __forceinline__ half4_ cvh4(f32x4 v) {
    return half4_{(_Float16)v[0], (_Float16)v[1], (_Float16)v[2], (_Float16)v[3]};
}

#define MFMA16(A, Bv, C) __builtin_amdgcn_mfma_f32_16x16x32_f16((A), (Bv), (C), 0, 0, 0)

__global__ void __launch_bounds__(512)
lstm4(const float* __restrict__ y,
      const float* __restrict__ Wih0, const float* __restrict__ Whh0,
      const float* __restrict__ bih0, const float* __restrict__ bhh0,
      const float* __restrict__ Wih1, const float* __restrict__ Whh1,
      const float* __restrict__ bih1, const float* __restrict__ bhh1,
      const float* __restrict__ Wa,  const float* __restrict__ ba,
      _Float16* __restrict__ seeds0, _Float16* __restrict__ seeds1,
      _Float16* __restrict__ h0r,
      int* __restrict__ flags, float* __restrict__ out)
{
    __shared__ _Float16 xbuf[8][16][KPAD];   // P0/P1 staging
    __shared__ _Float16 hbuf[2][16][KPAD];   // S0/S1 h state

    const int tid = threadIdx.x;
    const int w   = tid >> 6;
    const int l   = tid & 63;
    const int g   = l >> 4;
    const int cl  = l & 15;
    const int role = blockIdx.x & 3;     // 0=P0 1=S0 2=P1 3=S1
    const int bg   = blockIdx.x >> 2;
    const int b0   = bg * BCH;

    int* fg0 = flags;         // P0 -> S0: seeds0 ready
    int* fs0 = flags + 32;    // S0 -> P0: seeds0 slot credit
    int* fh0 = flags + 64;    // S0 -> P1: h0 chunk ready
    int* fp1 = flags + 96;    // P1 -> S0: h0 slot credit
    int* fg1 = flags + 128;   // P1 -> S1: seeds1 ready
    int* fs1 = flags + 160;   // S1 -> P1: seeds1 slot credit

    { // zero hbuf (initial h state for S roles)
        int* q = (int*)&hbuf[0][0][0];
        for (int i = tid; i < (int)(sizeof(hbuf) / 4); i += 512) q[i] = 0;
    }

    if (role == 0) {
        // ====================== P0: layer-0 input projection ======================
        half8 wf[4][4];
        #pragma unroll
        for (int gt = 0; gt < 4; ++gt) {
            const int grow = gt * 128 + w * 16 + cl;
            #pragma unroll
            for (int kt = 0; kt < 4; ++kt) {
                const float* pa = Wih0 + grow * H_ + kt * 32 + g * 8;
                f32x4 a0 = *(const f32x4*)(pa);
                f32x4 a1 = *(const f32x4*)(pa + 4);
                half8 fa;
                #pragma unroll
                for (int e = 0; e < 4; ++e) { fa[e] = (_Float16)a0[e]; fa[e + 4] = (_Float16)a1[e]; }
                wf[gt][kt] = fa;
            }
        }
        f32x4 bias[4];
        #pragma unroll
        for (int gt = 0; gt < 4; ++gt)
            #pragma unroll
            for (int r = 0; r < 4; ++r) {
                const int R = gt * 128 + w * 16 + g * 4 + r;
                bias[gt][r] = bih0[R] + bhh0[R];
            }
        __syncthreads();

        for (int c = 0; c < NCH; ++c) {
            if (tid == 0 && c >= RS) fwait(&fs0[bg], c - (RS - 1));
            __syncthreads();

            // stage y[b][k][c*8..+8) -> xbuf (f16)
            #pragma unroll
            for (int rr = 0; rr < 4; ++rr) {
                const int q = tid + rr * 512;
                const int b = q >> 7, k = q & 127;
                const float* src = y + ((size_t)((b0 + b) * H_ + k)) * T_ + c * 8;
                f32x4 v0 = *(const f32x4*)(src);
                f32x4 v1 = *(const f32x4*)(src + 4);
                #pragma unroll
                for (int e = 0; e < 4; ++e) {
                    xbuf[e][b][k]     = (_Float16)v0[e];
                    xbuf[e + 4][b][k] = (_Float16)v1[e];
                }
            }
            lds_barrier();

            _Float16* sb = seeds0 + (size_t)(bg * RS + (c & (RS - 1))) * SEEDSLOT;
            for (int s = 0; s < 8; ++s) {
                half8 xf[4];
                #pragma unroll
                for (int kt = 0; kt < 4; ++kt)
                    xf[kt] = *(const half8*)&xbuf[s][cl][kt * 32 + g * 8];
                #pragma unroll
                for (int gt = 0; gt < 4; ++gt) {
                    f32x4 acc = bias[gt];
                    #pragma unroll
                    for (int kt = 0; kt < 4; ++kt)
                        acc = MFMA16(wf[gt][kt], xf[kt], acc);
                    *(half4_*)(sb + ((size_t)(s * 4 + gt) * 512 + tid) * 4) = cvh4(acc);
                }
            }
            __syncthreads();                 // drain seed stores
            if (tid == 0) frel(&fg0[bg], c + 1);
            lds_barrier();                   // xbuf reuse safety
        }
    } else if (role == 1) {
        // ====================== S0: light recurrence, layer 0 ======================
        half8 whh[4][4];
        #pragma unroll
        for (int gt = 0; gt < 4; ++gt) {
            const int grow = gt * 128 + w * 16 + cl;
            #pragma unroll
            for (int kt = 0; kt < 4; ++kt) {
                const float* pb = Whh0 + grow * H_ + kt * 32 + g * 8;
                f32x4 c0 = *(const f32x4*)(pb);
                f32x4 c1 = *(const f32x4*)(pb + 4);
                half8 fb;
                #pragma unroll
                for (int e = 0; e < 4; ++e) { fb[e] = (_Float16)c0[e]; fb[e + 4] = (_Float16)c1[e]; }
                whh[gt][kt] = fb;
            }
        }
        float cst[4] = {0.f, 0.f, 0.f, 0.f};
        __syncthreads();

        for (int c = 0; c < NCH; ++c) {
            if (tid == 0) {
                fwait(&fg0[bg], c + 1);                       // seeds0 ready
                if (c >= RS) fwait(&fp1[bg], c - (RS - 1));   // h0 slot free
            }
            __syncthreads();

            const _Float16* sb = seeds0 + (size_t)(bg * RS + (c & (RS - 1))) * SEEDSLOT
                               + (size_t)tid * 4;
            _Float16* hb = h0r + (size_t)(bg * RS + (c & (RS - 1))) * H0SLOT;

            half4_ sd[2][4];
            #pragma unroll
            for (int gt = 0; gt < 4; ++gt)
                sd[0][gt] = *(const half4_*)(sb + (size_t)(0 * 4 + gt) * 2048);
            #pragma unroll
            for (int gt = 0; gt < 4; ++gt)
                sd[1][gt] = *(const half4_*)(sb + (size_t)(1 * 4 + gt) * 2048);

            #pragma unroll
            for (int s = 0; s < 8; ++s) {
                const int rd = (s ^ 1) & 1;
                const int wr = s & 1;

                half8 hf[4];
                #pragma unroll
                for (int kt = 0; kt < 4; ++kt)
                    hf[kt] = *(const half8*)&hbuf[rd][cl][kt * 32 + g * 8];

                f32x4 a0 = cvt4(sd[s & 1][0]);
                f32x4 a1 = cvt4(sd[s & 1][1]);
                f32x4 a2 = cvt4(sd[s & 1][2]);
                f32x4 a3 = cvt4(sd[s & 1][3]);
                if (s + 2 < 8) {
                    #pragma unroll
                    for (int gt = 0; gt < 4; ++gt)
                        sd[s & 1][gt] =
                            *(const half4_*)(sb + (size_t)((s + 2) * 4 + gt) * 2048);
                }

                #pragma unroll
                for (int kt = 0; kt < 4; ++kt) {
                    a0 = MFMA16(whh[0][kt], hf[kt], a0);
                    a1 = MFMA16(whh[1][kt], hf[kt], a1);
                    a2 = MFMA16(whh[2][kt], hf[kt], a2);
                    a3 = MFMA16(whh[3][kt], hf[kt], a3);
                }

                half4_ h4;
                #pragma unroll
                for (int r = 0; r < 4; ++r) {
                    const float is  = sigm_(a0[r]);
                    const float fs  = sigm_(a1[r]);
                    const float gt_ = tanh_(a2[r]);
                    const float os  = sigm_(a3[r]);
                    cst[r] = fs * cst[r] + is * gt_;
                    h4[r] = (_Float16)(os * tanh_(cst[r]));
                }
                const int u0 = w * 16 + g * 4;
                *(half4_*)&hbuf[wr][cl][u0] = h4;
                *(half4_*)(hb + (s * 16 + cl) * 128 + u0) = h4;

                if (s < 7) {
                    lds_barrier();
                } else {
                    __syncthreads();            // drain h0 stores + seed loads
                    if (tid == 0) {
                        frel(&fh0[bg], c + 1);  // h0 ready for P1
                        frel(&fs0[bg], c + 1);  // seeds0 slot free for P0
                    }
                }
            }
        }
    } else if (role == 2) {
        // ====================== P1: layer-1 input projection ======================
        half8 wf[4][4];
        #pragma unroll
        for (int gt = 0; gt < 4; ++gt) {
            const int grow = gt * 128 + w * 16 + cl;
            #pragma unroll
            for (int kt = 0; kt < 4; ++kt) {
                const float* pa = Wih1 + grow * H_ + kt * 32 + g * 8;
                f32x4 a0 = *(const f32x4*)(pa);
                f32x4 a1 = *(const f32x4*)(pa + 4);
                half8 fa;
                #pragma unroll
                for (int e = 0; e < 4; ++e) { fa[e] = (_Float16)a0[e]; fa[e + 4] = (_Float16)a1[e]; }
                wf[gt][kt] = fa;
            }
        }
        f32x4 bias[4];
        #pragma unroll
        for (int gt = 0; gt < 4; ++gt)
            #pragma unroll
            for (int r = 0; r < 4; ++r) {
                const int R = gt * 128 + w * 16 + g * 4 + r;
                bias[gt][r] = bih1[R] + bhh1[R];
            }
        __syncthreads();

        for (int c = 0; c < NCH; ++c) {
            if (tid == 0) {
                fwait(&fh0[bg], c + 1);                       // h0(c) ready
                if (c >= RS) fwait(&fs1[bg], c - (RS - 1));   // seeds1 slot free
            }
            __syncthreads();

            {   // stage h0 slot c -> xbuf (coalesced)
                const _Float16* sbh = h0r + (size_t)(bg * RS + (c & (RS - 1))) * H0SLOT;
                const int pq = tid >> 2;
                const int b = pq >> 3, trow = pq & 7;
                const int u0 = (tid & 3) * 32;
                const _Float16* src = sbh + (trow * 16 + b) * 128 + u0;
                #pragma unroll
                for (int e = 0; e < 4; ++e) {
                    half8 v = *(const half8*)(src + e * 8);
                    *(half8*)&xbuf[trow][b][u0 + e * 8] = v;
                }
            }
            lds_barrier();              // ds_writes done => src loads retired
            if (tid == 0) frel(&fp1[bg], c + 1);   // h0 slot free for S0

            _Float16* sb = seeds1 + (size_t)(bg * RS + (c & (RS - 1))) * SEEDSLOT;
            for (int s = 0; s < 8; ++s) {
                half8 xf[4];
                #pragma unroll
                for (int kt = 0; kt < 4; ++kt)
                    xf[kt] = *(const half8*)&xbuf[s][cl][kt * 32 + g * 8];
                #pragma unroll
                for (int gt = 0; gt < 4; ++gt) {
                    f32x4 acc = bias[gt];
                    #pragma unroll
                    for (int kt = 0; kt < 4; ++kt)
                        acc = MFMA16(wf[gt][kt], xf[kt], acc);
                    *(half4_*)(sb + ((size_t)(s * 4 + gt) * 512 + tid) * 4) = cvh4(acc);
                }
            }
            __syncthreads();                 // drain seeds1 stores
            if (tid == 0) frel(&fg1[bg], c + 1);
            lds_barrier();                   // xbuf reuse safety
        }
    } else {
        // ============ S1: light layer-1 recurrence + head ============
        half8 whh[4][4];
        #pragma unroll
        for (int gt = 0; gt < 4; ++gt) {
            const int grow = gt * 128 + w * 16 + cl;
            #pragma unroll
            for (int kt = 0; kt < 4; ++kt) {
                const float* pb = Whh1 + grow * H_ + kt * 32 + g * 8;
                f32x4 c0 = *(const f32x4*)(pb);
                f32x4 c1 = *(const f32x4*)(pb + 4);
                half8 fb;
                #pragma unroll
                for (int e = 0; e < 4; ++e) { fb[e] = (_Float16)c0[e]; fb[e + 4] = (_Float16)c1[e]; }
                whh[gt][kt] = fb;
            }
        }
        half8 waf[4];
        f32x4 ba4  = {0.f, 0.f, 0.f, 0.f};
        f32x4 oacc = {0.f, 0.f, 0.f, 0.f};
        #pragma unroll
        for (int kt = 0; kt < 4; ++kt) {
            const float* p = Wa + (w * 16 + cl) * H_ + kt * 32 + g * 8;
            f32x4 a0 = *(const f32x4*)(p);
            f32x4 a1 = *(const f32x4*)(p + 4);
            half8 f;
            #pragma unroll
            for (int e = 0; e < 4; ++e) { f[e] = (_Float16)a0[e]; f[e + 4] = (_Float16)a1[e]; }
            waf[kt] = f;
        }
        #pragma unroll
        for (int r = 0; r < 4; ++r) ba4[r] = ba[w * 16 + g * 4 + r];

        float cst[4] = {0.f, 0.f, 0.f, 0.f};
        __syncthreads();

        for (int c = 0; c < NCH; ++c) {
            if (tid == 0) fwait(&fg1[bg], c + 1);
            __syncthreads();

            const _Float16* sb = seeds1 + (size_t)(bg * RS + (c & (RS - 1))) * SEEDSLOT
                               + (size_t)tid * 4;
            half4_ sd[2][4];
            #pragma unroll
            for (int gt = 0; gt < 4; ++gt)
                sd[0][gt] = *(const half4_*)(sb + (size_t)(0 * 4 + gt) * 2048);
            #pragma unroll
            for (int gt = 0; gt < 4; ++gt)
                sd[1][gt] = *(const half4_*)(sb + (size_t)(1 * 4 + gt) * 2048);

            #pragma unroll
            for (int s = 0; s < 8; ++s) {
                const int t  = c * 8 + s;
                const int rd = (s ^ 1) & 1;
                const int wr = s & 1;

                half8 hf[4];       // h1(t-1)
                #pragma unroll
                for (int kt = 0; kt < 4; ++kt)
                    hf[kt] = *(const half8*)&hbuf[rd][cl][kt * 32 + g * 8];

                f32x4 a0 = cvt4(sd[s & 1][0]);
                f32x4 a1 = cvt4(sd[s & 1][1]);
                f32x4 a2 = cvt4(sd[s & 1][2]);
                f32x4 a3 = cvt4(sd[s & 1][3]);
                if (s + 2 < 8) {
                    #pragma unroll
                    for (int gt = 0; gt < 4; ++gt)
                        sd[s & 1][gt] =
                            *(const half4_*)(sb + (size_t)((s + 2) * 4 + gt) * 2048);
                }
                #pragma unroll
                for (int kt = 0; kt < 4; ++kt) {
                    a0 = MFMA16(whh[0][kt], hf[kt], a0);
                    a1 = MFMA16(whh[1][kt], hf[kt], a1);
                    a2 = MFMA16(whh[2][kt], hf[kt], a2);
                    a3 = MFMA16(whh[3][kt], hf[kt], a3);
                }

                if (t > 0) {     // head term for h1(t-1)
                    f32x4 aacc = ba4;
                    #pragma unroll
                    for (int kt = 0; kt < 4; ++kt) aacc = MFMA16(waf[kt], hf[kt], aacc);
                    #pragma unroll
                    for (int r = 0; r < 4; ++r) {
                        const float a = aacc[r];
                        oacc[r] += a * fmaxf(a, 0.f);
                    }
                }

                half4_ h4;
                #pragma unroll
                for (int r = 0; r < 4; ++r) {
                    const float is  = sigm_(a0[r]);
                    const float fs  = sigm_(a1[r]);
                    const float gt_ = tanh_(a2[r]);
                    const float os  = sigm_(a3[r]);
                    cst[r] = fs * cst[r] + is * gt_;
                    h4[r] = (_Float16)(os * tanh_(cst[r]));
                }
                const int u0 = w * 16 + g * 4;
                *(half4_*)&hbuf[wr][cl][u0] = h4;

                if (s < 7) {
                    lds_barrier();
                } else {
                    __syncthreads();               // seeds1 reads retired
                    if (tid == 0) frel(&fs1[bg], c + 1);
                }
            }
        }

        // final head term for h1(T-1) in hbuf[1]
        f32x4 aacc = ba4;
        #pragma unroll
        for (int kt = 0; kt < 4; ++kt) {
            const half8 hfv = *(const half8*)&hbuf[1][cl][kt * 32 + g * 8];
            aacc = MFMA16(waf[kt], hfv, aacc);
        }
        #pragma unroll
        for (int r = 0; r < 4; ++r) {
            const float a = aacc[r];
            oacc[r] += a * fmaxf(a, 0.f);
        }
        *(f32x4*)&out[(size_t)(b0 + cl) * H_ + w * 16 + g * 4] = oacc;
    }
}

extern "C" void kernel_launch(void* const* d_in, const int* in_sizes, int n_in,
                              void* d_out, int out_size, void* d_ws, size_t ws_size,
                              hipStream_t stream) {
    const float* y    = (const float*)d_in[0];
    const float* Wih0 = (const float*)d_in[1];
    const float* Whh0 = (const float*)d_in[2];
    const float* bih0 = (const float*)d_in[3];
    const float* bhh0 = (const float*)d_in[4];
    const float* Wih1 = (const float*)d_in[5];
    const float* Whh1 = (const float*)d_in[6];
    const float* bih1 = (const float*)d_in[7];
    const float* bhh1 = (const float*)d_in[8];
    const float* Wa   = (const float*)d_in[9];
    const float* ba   = (const float*)d_in[10];
    float* out = (float*)d_out;

    const size_t SEED_BYTES = (size_t)NBG * RS * SEEDSLOT * 2;   // 16 MiB each
    const size_t H0_BYTES   = (size_t)NBG * RS * H0SLOT * 2;     // 4 MiB
    char* p = (char*)d_ws;
    _Float16* seeds0 = (_Float16*)p;            p += SEED_BYTES;
    _Float16* seeds1 = (_Float16*)p;            p += SEED_BYTES;
    _Float16* h0r    = (_Float16*)p;            p += H0_BYTES;
    int*      flags  = (int*)p;

    hipMemsetAsync(flags, 0, 1024, stream);
    lstm4<<<4 * NBG, 512, 0, stream>>>(y, Wih0, Whh0, bih0, bhh0,
                                       Wih1, Whh1, bih1, bhh1, Wa, ba,
                                       seeds0, seeds1, h0r, flags, out);
}

// Round 17
// 807.952 us; speedup vs baseline: 3.5876x; 1.3373x over previous
//
#include <hip/hip_runtime.h>

// LSTMFeatureExtractor: 2-layer LSTM (H=128) over B=512, T=512, + a*relu(a) head.
// FINAL = Round 12 (session best: 806us total, kernel 840us). 3-role pipeline,
// 96 blocks x 512 thr:
//  P0 (role 0): seeds0 = bias0 + x@Wih0^T per 8-step chunk into a 4-deep f16
//               ring, stored per-consumer-thread ([s][gt][tid][4]): coalesced.
//  S0 (role 1): light recurrence layer 0: acc = cvt(seed) + h@Whh0^T
//               (16 MFMAs, 4 ds_read, no staging), nonlin, h -> h0 ring (4-deep).
//  S1 (role 2): layer-1 recurrence + head: stages h0 chunk to LDS, ih+hh+head
//               MFMAs, nonlin, a*relu(a) accumulation -> out.
// Flags: fg0 P0->S0 (seeds ready), fs0 S0->P0 (seed slot credit),
//        fh0 S0->S1 (h0 ready),    fs1 S1->S0 (h0 slot credit).
// Session evidence: r13 (heavier S0), r14 (scattered chain reads), r15 (merged
// P-stage), r16 (4-role) all regressed 12-260% vs this structure.

typedef _Float16 half8  __attribute__((ext_vector_type(8)));
typedef _Float16 half4_ __attribute__((ext_vector_type(4)));
typedef float    f32x4  __attribute__((ext_vector_type(4)));

#define H_    128
#define T_    512
#define B_    512
#define BCH   16
#define NBG   32
#define NCH   64                  // 8-step chunks
#define KPAD  136
#define RS    4                   // seed ring depth
#define RH    4                   // h0 ring depth
#define SEEDSLOT (8 * 4 * 512 * 4)    // halves per (bg,slot): 65536 (128KB)
#define H0SLOT   (8 * 16 * 128)       // halves per (bg,slot): 16384 (32KB)

#define LOG2E 1.44269504089f

__device__ __forceinline__ float sigm_(float x) {
    return __builtin_amdgcn_rcpf(1.f + __builtin_amdgcn_exp2f(-LOG2E * x));
}
__device__ __forceinline__ float tanh_(float x) {
    return 1.f - 2.f * __builtin_amdgcn_rcpf(1.f + __builtin_amdgcn_exp2f((2.f * LOG2E) * x));
}
__device__ __forceinline__ void lds_barrier() {
    __builtin_amdgcn_sched_barrier(0);
    asm volatile("s_waitcnt lgkmcnt(0)" ::: "memory");
    __builtin_amdgcn_sched_barrier(0);
    __builtin_amdgcn_s_barrier();
    __builtin_amdgcn_sched_barrier(0);
}
__device__ __forceinline__ void fwait(const int* p, int tgt) {
    while (__hip_atomic_load(p, __ATOMIC_ACQUIRE, __HIP_MEMORY_SCOPE_AGENT) < tgt)
        __builtin_amdgcn_s_sleep(2);
}
__device__ __forceinline__ void frel(int* p, int v) {
    __hip_atomic_store(p, v, __ATOMIC_RELEASE, __HIP_MEMORY_SCOPE_AGENT);
}
__device__ __forceinline__ f32x4 cvt4(half4_ h) {
    return f32x4{(float)h[0], (float)h[1], (float)h[2], (float)h[3]};
}
__device__ __forceinline__ half4_ cvh4(f32x4 v) {
    return half4_{(_Float16)v[0], (_Float16)v[1], (_Float16)v[2], (_Float16)v[3]};
}

#define MFMA16(A, Bv, C) __builtin_amdgcn_mfma_f32_16x16x32_f16((A), (Bv), (C), 0, 0, 0)

__global__ void __launch_bounds__(512)
lstm3(const float* __restrict__ y,
      const float* __restrict__ Wih0, const float* __restrict__ Whh0,
      const float* __restrict__ bih0, const float* __restrict__ bhh0,
      const float* __restrict__ Wih1, const float* __restrict__ Whh1,
      const float* __restrict__ bih1, const float* __restrict__ bhh1,
      const float* __restrict__ Wa,  const float* __restrict__ ba,
      _Float16* __restrict__ seeds, _Float16* __restrict__ h0r,
      int* __restrict__ flags, float* __restrict__ out)
{
    __shared__ _Float16 xbuf[8][16][KPAD];
    __shared__ _Float16 hbuf[2][16][KPAD];

    const int tid = threadIdx.x;
    const int w   = tid >> 6;
    const int l   = tid & 63;
    const int g   = l >> 4;
    const int cl  = l & 15;
    const int role = blockIdx.x % 3;     // 0=P0 1=S0 2=S1
    const int bg   = blockIdx.x / 3;
    const int b0   = bg * BCH;

    int* fg0 = flags;        // P0 -> S0: seeds chunk ready
    int* fs0 = flags + 32;   // S0 -> P0: seed slot credit
    int* fh0 = flags + 64;   // S0 -> S1: h0 chunk ready
    int* fs1 = flags + 96;   // S1 -> S0: h0 slot credit

    { // zero hbuf (initial h state for S roles)
        int* q = (int*)&hbuf[0][0][0];
        for (int i = tid; i < (int)(sizeof(hbuf) / 4); i += 512) q[i] = 0;
    }

    if (role == 0) {
        // ====================== P0: layer-0 input projection ======================
        half8 wf[4][4];
        #pragma unroll
        for (int gt = 0; gt < 4; ++gt) {
            const int grow = gt * 128 + w * 16 + cl;
            #pragma unroll
            for (int kt = 0; kt < 4; ++kt) {
                const float* pa = Wih0 + grow * H_ + kt * 32 + g * 8;
                f32x4 a0 = *(const f32x4*)(pa);
                f32x4 a1 = *(const f32x4*)(pa + 4);
                half8 fa;
                #pragma unroll
                for (int e = 0; e < 4; ++e) { fa[e] = (_Float16)a0[e]; fa[e + 4] = (_Float16)a1[e]; }
                wf[gt][kt] = fa;
            }
        }
        f32x4 bias[4];
        #pragma unroll
        for (int gt = 0; gt < 4; ++gt)
            #pragma unroll
            for (int r = 0; r < 4; ++r) {
                const int R = gt * 128 + w * 16 + g * 4 + r;
                bias[gt][r] = bih0[R] + bhh0[R];
            }
        __syncthreads();

        for (int c = 0; c < NCH; ++c) {
            if (tid == 0 && c >= RS) fwait(&fs0[bg], c - (RS - 1));
            __syncthreads();

            // stage y[b][k][c*8..+8) -> xbuf (f16)
            #pragma unroll
            for (int rr = 0; rr < 4; ++rr) {
                const int q = tid + rr * 512;
                const int b = q >> 7, k = q & 127;
                const float* src = y + ((size_t)((b0 + b) * H_ + k)) * T_ + c * 8;
                f32x4 v0 = *(const f32x4*)(src);
                f32x4 v1 = *(const f32x4*)(src + 4);
                #pragma unroll
                for (int e = 0; e < 4; ++e) {
                    xbuf[e][b][k]     = (_Float16)v0[e];
                    xbuf[e + 4][b][k] = (_Float16)v1[e];
                }
            }
            lds_barrier();

            _Float16* sb = seeds + (size_t)(bg * RS + (c & (RS - 1))) * SEEDSLOT;
            for (int s = 0; s < 8; ++s) {
                half8 xf[4];
                #pragma unroll
                for (int kt = 0; kt < 4; ++kt)
                    xf[kt] = *(const half8*)&xbuf[s][cl][kt * 32 + g * 8];
                #pragma unroll
                for (int gt = 0; gt < 4; ++gt) {
                    f32x4 acc = bias[gt];
                    #pragma unroll
                    for (int kt = 0; kt < 4; ++kt)
                        acc = MFMA16(wf[gt][kt], xf[kt], acc);
                    // per-consumer-thread layout: [(s*4+gt)*512 + tid]*4 halves
                    *(half4_*)(sb + ((size_t)(s * 4 + gt) * 512 + tid) * 4) = cvh4(acc);
                }
            }
            __syncthreads();                 // drain seed stores (vmcnt)
            if (tid == 0) frel(&fg0[bg], c + 1);
        }
    } else if (role == 1) {
        // ====================== S0: light recurrence, layer 0 ======================
        half8 whh[4][4];
        #pragma unroll
        for (int gt = 0; gt < 4; ++gt) {
            const int grow = gt * 128 + w * 16 + cl;
            #pragma unroll
            for (int kt = 0; kt < 4; ++kt) {
                const float* pb = Whh0 + grow * H_ + kt * 32 + g * 8;
                f32x4 c0 = *(const f32x4*)(pb);
                f32x4 c1 = *(const f32x4*)(pb + 4);
                half8 fb;
                #pragma unroll
                for (int e = 0; e < 4; ++e) { fb[e] = (_Float16)c0[e]; fb[e + 4] = (_Float16)c1[e]; }
                whh[gt][kt] = fb;
            }
        }
        float cst[4] = {0.f, 0.f, 0.f, 0.f};
        __syncthreads();

        for (int c = 0; c < NCH; ++c) {
            if (tid == 0) {
                fwait(&fg0[bg], c + 1);                       // seeds ready
                if (c >= RH) fwait(&fs1[bg], c - (RH - 1));   // h0 slot free
            }
            __syncthreads();

            const _Float16* sb = seeds + (size_t)(bg * RS + (c & (RS - 1))) * SEEDSLOT
                               + (size_t)tid * 4;
            _Float16* hb = h0r + (size_t)(bg * RH + (c & (RH - 1))) * H0SLOT;

            half4_ sd[2][4];
            #pragma unroll
            for (int gt = 0; gt < 4; ++gt)
                sd[0][gt] = *(const half4_*)(sb + (size_t)(0 * 4 + gt) * 2048);
            #pragma unroll
            for (int gt = 0; gt < 4; ++gt)
                sd[1][gt] = *(const half4_*)(sb + (size_t)(1 * 4 + gt) * 2048);

            #pragma unroll
            for (int s = 0; s < 8; ++s) {
                const int rd = (s ^ 1) & 1;
                const int wr = s & 1;

                half8 hf[4];
                #pragma unroll
                for (int kt = 0; kt < 4; ++kt)
                    hf[kt] = *(const half8*)&hbuf[rd][cl][kt * 32 + g * 8];

                f32x4 a0 = cvt4(sd[s & 1][0]);
                f32x4 a1 = cvt4(sd[s & 1][1]);
                f32x4 a2 = cvt4(sd[s & 1][2]);
                f32x4 a3 = cvt4(sd[s & 1][3]);
                if (s + 2 < 8) {
                    #pragma unroll
                    for (int gt = 0; gt < 4; ++gt)
                        sd[s & 1][gt] =
                            *(const half4_*)(sb + (size_t)((s + 2) * 4 + gt) * 2048);
                }

                #pragma unroll
                for (int kt = 0; kt < 4; ++kt) {
                    a0 = MFMA16(whh[0][kt], hf[kt], a0);
                    a1 = MFMA16(whh[1][kt], hf[kt], a1);
                    a2 = MFMA16(whh[2][kt], hf[kt], a2);
                    a3 = MFMA16(whh[3][kt], hf[kt], a3);
                }

                half4_ h4;
                #pragma unroll
                for (int r = 0; r < 4; ++r) {
                    const float is  = sigm_(a0[r]);
                    const float fs  = sigm_(a1[r]);
                    const float gt_ = tanh_(a2[r]);
                    const float os  = sigm_(a3[r]);
                    cst[r] = fs * cst[r] + is * gt_;
                    h4[r] = (_Float16)(os * tanh_(cst[r]));
                }
                const int u0 = w * 16 + g * 4;
                *(half4_*)&hbuf[wr][cl][u0] = h4;
                *(half4_*)(hb + (s * 16 + cl) * 128 + u0) = h4;

                if (s < 7) {
                    lds_barrier();
                } else {
                    __syncthreads();            // drain h0 stores + seed loads
                    if (tid == 0) {
                        frel(&fh0[bg], c + 1);  // h0 chunk ready for S1
                        frel(&fs0[bg], c + 1);  // seed slot free for P0
                    }
                }
            }
        }
    } else {
        // ====================== S1: layer-1 recurrence + head ======================
        half8 wihf[4][4], whhf[4][4];
        #pragma unroll
        for (int gt = 0; gt < 4; ++gt) {
            const int grow = gt * 128 + w * 16 + cl;
            #pragma unroll
            for (int kt = 0; kt < 4; ++kt) {
                const float* pa = Wih1 + grow * H_ + kt * 32 + g * 8;
                const float* pb = Whh1 + grow * H_ + kt * 32 + g * 8;
                f32x4 a0 = *(const f32x4*)(pa);
                f32x4 a1 = *(const f32x4*)(pa + 4);
                f32x4 c0 = *(const f32x4*)(pb);
                f32x4 c1 = *(const f32x4*)(pb + 4);
                half8 fa, fb;
                #pragma unroll
                for (int e = 0; e < 4; ++e) {
                    fa[e] = (_Float16)a0[e]; fa[e + 4] = (_Float16)a1[e];
                    fb[e] = (_Float16)c0[e]; fb[e + 4] = (_Float16)c1[e];
                }
                wihf[gt][kt] = fa; whhf[gt][kt] = fb;
            }
        }
        f32x4 bias[4];
        #pragma unroll
        for (int gt = 0; gt < 4; ++gt)
            #pragma unroll
            for (int r = 0; r < 4; ++r) {
                const int R = gt * 128 + w * 16 + g * 4 + r;
                bias[gt][r] = bih1[R] + bhh1[R];
            }
        half8 waf[4];
        f32x4 ba4  = {0.f, 0.f, 0.f, 0.f};
        f32x4 oacc = {0.f, 0.f, 0.f, 0.f};
        #pragma unroll
        for (int kt = 0; kt < 4; ++kt) {
            const float* p = Wa + (w * 16 + cl) * H_ + kt * 32 + g * 8;
            f32x4 a0 = *(const f32x4*)(p);
            f32x4 a1 = *(const f32x4*)(p + 4);
            half8 f;
            #pragma unroll
            for (int e = 0; e < 4; ++e) { f[e] = (_Float16)a0[e]; f[e + 4] = (_Float16)a1[e]; }
            waf[kt] = f;
        }
        #pragma unroll
        for (int r = 0; r < 4; ++r) ba4[r] = ba[w * 16 + g * 4 + r];

        float cst[4] = {0.f, 0.f, 0.f, 0.f};
        __syncthreads();

        for (int t = 0; t < T_; ++t) {
            const int tb = t & 7;
            if (tb == 0) {
                const int c = t >> 3;
                if (tid == 0) fwait(&fh0[bg], c + 1);
                __syncthreads();
                // stage h0 ring slot -> xbuf (coalesced half8)
                const _Float16* sbh = h0r + (size_t)(bg * RH + (c & (RH - 1))) * H0SLOT;
                const int pq = tid >> 2;
                const int b = pq >> 3, trow = pq & 7;
                const int u0 = (tid & 3) * 32;
                const _Float16* src = sbh + (trow * 16 + b) * 128 + u0;
                #pragma unroll
                for (int e = 0; e < 4; ++e) {
                    half8 v = *(const half8*)(src + e * 8);
                    *(half8*)&xbuf[trow][b][u0 + e * 8] = v;
                }
                lds_barrier();
                if (tid == 0) frel(&fs1[bg], c + 1);   // slot consumed
            }

            const int rd = (t ^ 1) & 1;
            const int wr = t & 1;

            f32x4 ai0 = bias[0], ai1 = bias[1], ai2 = bias[2], ai3 = bias[3];
            f32x4 ah0 = {0,0,0,0}, ah1 = {0,0,0,0}, ah2 = {0,0,0,0}, ah3 = {0,0,0,0};
            half8 hf[4];
            #pragma unroll
            for (int kt = 0; kt < 4; ++kt) {
                const int ko = kt * 32 + g * 8;
                const half8 xf = *(const half8*)&xbuf[tb][cl][ko];
                hf[kt]         = *(const half8*)&hbuf[rd][cl][ko];
                ai0 = MFMA16(wihf[0][kt], xf, ai0);
                ai1 = MFMA16(wihf[1][kt], xf, ai1);
                ai2 = MFMA16(wihf[2][kt], xf, ai2);
                ai3 = MFMA16(wihf[3][kt], xf, ai3);
                ah0 = MFMA16(whhf[0][kt], hf[kt], ah0);
                ah1 = MFMA16(whhf[1][kt], hf[kt], ah1);
                ah2 = MFMA16(whhf[2][kt], hf[kt], ah2);
                ah3 = MFMA16(whhf[3][kt], hf[kt], ah3);
            }

            if (t > 0) {   // head term for h1(t-1)
                f32x4 aacc = ba4;
                #pragma unroll
                for (int kt = 0; kt < 4; ++kt) aacc = MFMA16(waf[kt], hf[kt], aacc);
                #pragma unroll
                for (int r = 0; r < 4; ++r) {
                    const float a = aacc[r];
                    oacc[r] += a * fmaxf(a, 0.f);
                }
            }

            half4_ h4;
            #pragma unroll
            for (int r = 0; r < 4; ++r) {
                const float i_ = ai0[r] + ah0[r];
                const float f_ = ai1[r] + ah1[r];
                const float g_ = ai2[r] + ah2[r];
                const float o_ = ai3[r] + ah3[r];
                const float is = sigm_(i_);
                const float fs = sigm_(f_);
                const float gt_ = tanh_(g_);
                const float os = sigm_(o_);
                cst[r] = fs * cst[r] + is * gt_;
                h4[r] = (_Float16)(os * tanh_(cst[r]));
            }
            const int u0 = w * 16 + g * 4;
            *(half4_*)&hbuf[wr][cl][u0] = h4;
            lds_barrier();
        }

        // final head term for h1(T-1) in hbuf[1]
        f32x4 aacc = ba4;
        #pragma unroll
        for (int kt = 0; kt < 4; ++kt) {
            const half8 hfv = *(const half8*)&hbuf[1][cl][kt * 32 + g * 8];
            aacc = MFMA16(waf[kt], hfv, aacc);
        }
        #pragma unroll
        for (int r = 0; r < 4; ++r) {
            const float a = aacc[r];
            oacc[r] += a * fmaxf(a, 0.f);
        }
        *(f32x4*)&out[(size_t)(b0 + cl) * H_ + w * 16 + g * 4] = oacc;
    }
}

extern "C" void kernel_launch(void* const* d_in, const int* in_sizes, int n_in,
                              void* d_out, int out_size, void* d_ws, size_t ws_size,
                              hipStream_t stream) {
    const float* y    = (const float*)d_in[0];
    const float* Wih0 = (const float*)d_in[1];
    const float* Whh0 = (const float*)d_in[2];
    const float* bih0 = (const float*)d_in[3];
    const float* bhh0 = (const float*)d_in[4];
    const float* Wih1 = (const float*)d_in[5];
    const float* Whh1 = (const float*)d_in[6];
    const float* bih1 = (const float*)d_in[7];
    const float* bhh1 = (const float*)d_in[8];
    const float* Wa   = (const float*)d_in[9];
    const float* ba   = (const float*)d_in[10];
    float* out = (float*)d_out;

    const size_t SEED_BYTES = (size_t)NBG * RS * SEEDSLOT * 2;   // 16 MiB
    const size_t H0_BYTES   = (size_t)NBG * RH * H0SLOT * 2;     // 4 MiB
    char* p = (char*)d_ws;
    _Float16* seeds = (_Float16*)p;             p += SEED_BYTES;
    _Float16* h0r   = (_Float16*)p;             p += H0_BYTES;
    int*      flags = (int*)p;

    hipMemsetAsync(flags, 0, 512, stream);
    lstm3<<<3 * NBG, 512, 0, stream>>>(y, Wih0, Whh0, bih0, bhh0,
                                       Wih1, Whh1, bih1, bhh1, Wa, ba,
                                       seeds, h0r, flags, out);
}

// Round 18
// 781.130 us; speedup vs baseline: 3.7107x; 1.0343x over previous
//
#include <hip/hip_runtime.h>

// LSTMFeatureExtractor: 2-layer LSTM (H=128) over B=512, T=512, + a*relu(a) head.
// Round 18 = round-12 structure VERBATIM + ONE mechanism change: the pipeline
// handoff no longer uses acquire/release cache maintenance (agent-scope
// release=buffer_wbl2 / acquire=buffer_inv on gfx950 walk+invalidate the whole
// XCD L2 every chunk — the suspected ~1500cyc/step concurrency tax). Instead:
//  - ALL ring data (seeds, h0) moves via 8-byte RELAXED agent atomics
//    (global_*_dwordx2 sc0 sc1: bypass L1/L2, served by the coherent L3).
//  - flag release = relaxed agent fetch_max RMW (coherence-point op, no wbl2);
//    flag wait = relaxed poll (r9-proven to observe remote updates), no fence.
//  - ordering: frel always follows a __syncthreads() whose implicit vmcnt(0)
//    drains every wave's sc0sc1 data stores to L3 first.

typedef _Float16 half8  __attribute__((ext_vector_type(8)));
typedef _Float16 half4_ __attribute__((ext_vector_type(4)));
typedef float    f32x4  __attribute__((ext_vector_type(4)));

#define H_    128
#define T_    512
#define B_    512
#define BCH   16
#define NBG   32
#define NCH   64                  // 8-step chunks
#define KPAD  136
#define RS    4                   // seed ring depth
#define RH    4                   // h0 ring depth
#define SEEDSLOT (8 * 4 * 512 * 4)    // halves per (bg,slot): 65536 (128KB)
#define H0SLOT   (8 * 16 * 128)       // halves per (bg,slot): 16384 (32KB)

#define LOG2E 1.44269504089f

__device__ __forceinline__ float sigm_(float x) {
    return __builtin_amdgcn_rcpf(1.f + __builtin_amdgcn_exp2f(-LOG2E * x));
}
__device__ __forceinline__ float tanh_(float x) {
    return 1.f - 2.f * __builtin_amdgcn_rcpf(1.f + __builtin_amdgcn_exp2f((2.f * LOG2E) * x));
}
__device__ __forceinline__ void lds_barrier() {
    __builtin_amdgcn_sched_barrier(0);
    asm volatile("s_waitcnt lgkmcnt(0)" ::: "memory");
    __builtin_amdgcn_sched_barrier(0);
    __builtin_amdgcn_s_barrier();
    __builtin_amdgcn_sched_barrier(0);
}
// relaxed poll: no buffer_inv (r9-proven to observe remote updates)
__device__ __forceinline__ void fwait(const int* p, int tgt) {
    while (__hip_atomic_load(p, __ATOMIC_RELAXED, __HIP_MEMORY_SCOPE_AGENT) < tgt)
        __builtin_amdgcn_s_sleep(2);
}
// relaxed RMW release: executes at the coherence point, NO buffer_wbl2.
// Callers invoke this only after a __syncthreads() (drains vmcnt for all waves).
__device__ __forceinline__ void frel(int* p, int v) {
    __hip_atomic_fetch_max(p, v, __ATOMIC_RELAXED, __HIP_MEMORY_SCOPE_AGENT);
}
// 8-byte coherent data movers: relaxed agent atomics -> sc0 sc1, L3-served.
__device__ __forceinline__ void st8(_Float16* p, half4_ v) {
    unsigned long long u;
    __builtin_memcpy(&u, &v, 8);
    __hip_atomic_store((unsigned long long*)p, u, __ATOMIC_RELAXED,
                       __HIP_MEMORY_SCOPE_AGENT);
}
__device__ __forceinline__ half4_ ld8(const _Float16* p) {
    unsigned long long u =
        __hip_atomic_load((const unsigned long long*)p, __ATOMIC_RELAXED,
                          __HIP_MEMORY_SCOPE_AGENT);
    half4_ v;
    __builtin_memcpy(&v, &u, 8);
    return v;
}
__device__ __forceinline__ f32x4 cvt4(half4_ h) {
    return f32x4{(float)h[0], (float)h[1], (float)h[2], (float)h[3]};
}
__device__ __forceinline__ half4_ cvh4(f32x4 v) {
    return half4_{(_Float16)v[0], (_Float16)v[1], (_Float16)v[2], (_Float16)v[3]};
}

#define MFMA16(A, Bv, C) __builtin_amdgcn_mfma_f32_16x16x32_f16((A), (Bv), (C), 0, 0, 0)

__global__ void __launch_bounds__(512)
lstm3(const float* __restrict__ y,
      const float* __restrict__ Wih0, const float* __restrict__ Whh0,
      const float* __restrict__ bih0, const float* __restrict__ bhh0,
      const float* __restrict__ Wih1, const float* __restrict__ Whh1,
      const float* __restrict__ bih1, const float* __restrict__ bhh1,
      const float* __restrict__ Wa,  const float* __restrict__ ba,
      _Float16* __restrict__ seeds, _Float16* __restrict__ h0r,
      int* __restrict__ flags, float* __restrict__ out)
{
    __shared__ _Float16 xbuf[8][16][KPAD];
    __shared__ _Float16 hbuf[2][16][KPAD];

    const int tid = threadIdx.x;
    const int w   = tid >> 6;
    const int l   = tid & 63;
    const int g   = l >> 4;
    const int cl  = l & 15;
    const int role = blockIdx.x % 3;     // 0=P0 1=S0 2=S1
    const int bg   = blockIdx.x / 3;
    const int b0   = bg * BCH;

    int* fg0 = flags;        // P0 -> S0: seeds chunk ready
    int* fs0 = flags + 32;   // S0 -> P0: seed slot credit
    int* fh0 = flags + 64;   // S0 -> S1: h0 chunk ready
    int* fs1 = flags + 96;   // S1 -> S0: h0 slot credit

    { // zero hbuf (initial h state for S roles)
        int* q = (int*)&hbuf[0][0][0];
        for (int i = tid; i < (int)(sizeof(hbuf) / 4); i += 512) q[i] = 0;
    }

    if (role == 0) {
        // ====================== P0: layer-0 input projection ======================
        half8 wf[4][4];
        #pragma unroll
        for (int gt = 0; gt < 4; ++gt) {
            const int grow = gt * 128 + w * 16 + cl;
            #pragma unroll
            for (int kt = 0; kt < 4; ++kt) {
                const float* pa = Wih0 + grow * H_ + kt * 32 + g * 8;
                f32x4 a0 = *(const f32x4*)(pa);
                f32x4 a1 = *(const f32x4*)(pa + 4);
                half8 fa;
                #pragma unroll
                for (int e = 0; e < 4; ++e) { fa[e] = (_Float16)a0[e]; fa[e + 4] = (_Float16)a1[e]; }
                wf[gt][kt] = fa;
            }
        }
        f32x4 bias[4];
        #pragma unroll
        for (int gt = 0; gt < 4; ++gt)
            #pragma unroll
            for (int r = 0; r < 4; ++r) {
                const int R = gt * 128 + w * 16 + g * 4 + r;
                bias[gt][r] = bih0[R] + bhh0[R];
            }
        __syncthreads();

        for (int c = 0; c < NCH; ++c) {
            if (tid == 0 && c >= RS) fwait(&fs0[bg], c - (RS - 1));
            __syncthreads();

            // stage y[b][k][c*8..+8) -> xbuf (f16)
            #pragma unroll
            for (int rr = 0; rr < 4; ++rr) {
                const int q = tid + rr * 512;
                const int b = q >> 7, k = q & 127;
                const float* src = y + ((size_t)((b0 + b) * H_ + k)) * T_ + c * 8;
                f32x4 v0 = *(const f32x4*)(src);
                f32x4 v1 = *(const f32x4*)(src + 4);
                #pragma unroll
                for (int e = 0; e < 4; ++e) {
                    xbuf[e][b][k]     = (_Float16)v0[e];
                    xbuf[e + 4][b][k] = (_Float16)v1[e];
                }
            }
            lds_barrier();

            _Float16* sb = seeds + (size_t)(bg * RS + (c & (RS - 1))) * SEEDSLOT;
            for (int s = 0; s < 8; ++s) {
                half8 xf[4];
                #pragma unroll
                for (int kt = 0; kt < 4; ++kt)
                    xf[kt] = *(const half8*)&xbuf[s][cl][kt * 32 + g * 8];
                #pragma unroll
                for (int gt = 0; gt < 4; ++gt) {
                    f32x4 acc = bias[gt];
                    #pragma unroll
                    for (int kt = 0; kt < 4; ++kt)
                        acc = MFMA16(wf[gt][kt], xf[kt], acc);
                    // per-consumer-thread layout, coherent 8B store (sc0 sc1)
                    st8(sb + ((size_t)(s * 4 + gt) * 512 + tid) * 4, cvh4(acc));
                }
            }
            __syncthreads();                 // drains all waves' sc0sc1 stores
            if (tid == 0) frel(&fg0[bg], c + 1);
        }
    } else if (role == 1) {
        // ====================== S0: light recurrence, layer 0 ======================
        half8 whh[4][4];
        #pragma unroll
        for (int gt = 0; gt < 4; ++gt) {
            const int grow = gt * 128 + w * 16 + cl;
            #pragma unroll
            for (int kt = 0; kt < 4; ++kt) {
                const float* pb = Whh0 + grow * H_ + kt * 32 + g * 8;
                f32x4 c0 = *(const f32x4*)(pb);
                f32x4 c1 = *(const f32x4*)(pb + 4);
                half8 fb;
                #pragma unroll
                for (int e = 0; e < 4; ++e) { fb[e] = (_Float16)c0[e]; fb[e + 4] = (_Float16)c1[e]; }
                whh[gt][kt] = fb;
            }
        }
        float cst[4] = {0.f, 0.f, 0.f, 0.f};
        __syncthreads();

        for (int c = 0; c < NCH; ++c) {
            if (tid == 0) {
                fwait(&fg0[bg], c + 1);                       // seeds ready
                if (c >= RH) fwait(&fs1[bg], c - (RH - 1));   // h0 slot free
            }
            __syncthreads();

            const _Float16* sb = seeds + (size_t)(bg * RS + (c & (RS - 1))) * SEEDSLOT
                               + (size_t)tid * 4;
            _Float16* hb = h0r + (size_t)(bg * RH + (c & (RH - 1))) * H0SLOT;

            half4_ sd[2][4];
            #pragma unroll
            for (int gt = 0; gt < 4; ++gt)
                sd[0][gt] = ld8(sb + (size_t)(0 * 4 + gt) * 2048);
            #pragma unroll
            for (int gt = 0; gt < 4; ++gt)
                sd[1][gt] = ld8(sb + (size_t)(1 * 4 + gt) * 2048);

            #pragma unroll
            for (int s = 0; s < 8; ++s) {
                const int rd = (s ^ 1) & 1;
                const int wr = s & 1;

                half8 hf[4];
                #pragma unroll
                for (int kt = 0; kt < 4; ++kt)
                    hf[kt] = *(const half8*)&hbuf[rd][cl][kt * 32 + g * 8];

                f32x4 a0 = cvt4(sd[s & 1][0]);
                f32x4 a1 = cvt4(sd[s & 1][1]);
                f32x4 a2 = cvt4(sd[s & 1][2]);
                f32x4 a3 = cvt4(sd[s & 1][3]);
                if (s + 2 < 8) {
                    #pragma unroll
                    for (int gt = 0; gt < 4; ++gt)
                        sd[s & 1][gt] = ld8(sb + (size_t)((s + 2) * 4 + gt) * 2048);
                }

                #pragma unroll
                for (int kt = 0; kt < 4; ++kt) {
                    a0 = MFMA16(whh[0][kt], hf[kt], a0);
                    a1 = MFMA16(whh[1][kt], hf[kt], a1);
                    a2 = MFMA16(whh[2][kt], hf[kt], a2);
                    a3 = MFMA16(whh[3][kt], hf[kt], a3);
                }

                half4_ h4;
                #pragma unroll
                for (int r = 0; r < 4; ++r) {
                    const float is  = sigm_(a0[r]);
                    const float fs  = sigm_(a1[r]);
                    const float gt_ = tanh_(a2[r]);
                    const float os  = sigm_(a3[r]);
                    cst[r] = fs * cst[r] + is * gt_;
                    h4[r] = (_Float16)(os * tanh_(cst[r]));
                }
                const int u0 = w * 16 + g * 4;
                *(half4_*)&hbuf[wr][cl][u0] = h4;
                st8(hb + (s * 16 + cl) * 128 + u0, h4);   // coherent h0 store

                if (s < 7) {
                    lds_barrier();
                } else {
                    __syncthreads();            // drains h0 stores + seed loads
                    if (tid == 0) {
                        frel(&fh0[bg], c + 1);  // h0 chunk ready for S1
                        frel(&fs0[bg], c + 1);  // seed slot free for P0
                    }
                }
            }
        }
    } else {
        // ====================== S1: layer-1 recurrence + head ======================
        half8 wihf[4][4], whhf[4][4];
        #pragma unroll
        for (int gt = 0; gt < 4; ++gt) {
            const int grow = gt * 128 + w * 16 + cl;
            #pragma unroll
            for (int kt = 0; kt < 4; ++kt) {
                const float* pa = Wih1 + grow * H_ + kt * 32 + g * 8;
                const float* pb = Whh1 + grow * H_ + kt * 32 + g * 8;
                f32x4 a0 = *(const f32x4*)(pa);
                f32x4 a1 = *(const f32x4*)(pa + 4);
                f32x4 c0 = *(const f32x4*)(pb);
                f32x4 c1 = *(const f32x4*)(pb + 4);
                half8 fa, fb;
                #pragma unroll
                for (int e = 0; e < 4; ++e) {
                    fa[e] = (_Float16)a0[e]; fa[e + 4] = (_Float16)a1[e];
                    fb[e] = (_Float16)c0[e]; fb[e + 4] = (_Float16)c1[e];
                }
                wihf[gt][kt] = fa; whhf[gt][kt] = fb;
            }
        }
        f32x4 bias[4];
        #pragma unroll
        for (int gt = 0; gt < 4; ++gt)
            #pragma unroll
            for (int r = 0; r < 4; ++r) {
                const int R = gt * 128 + w * 16 + g * 4 + r;
                bias[gt][r] = bih1[R] + bhh1[R];
            }
        half8 waf[4];
        f32x4 ba4  = {0.f, 0.f, 0.f, 0.f};
        f32x4 oacc = {0.f, 0.f, 0.f, 0.f};
        #pragma unroll
        for (int kt = 0; kt < 4; ++kt) {
            const float* p = Wa + (w * 16 + cl) * H_ + kt * 32 + g * 8;
            f32x4 a0 = *(const f32x4*)(p);
            f32x4 a1 = *(const f32x4*)(p + 4);
            half8 f;
            #pragma unroll
            for (int e = 0; e < 4; ++e) { f[e] = (_Float16)a0[e]; f[e + 4] = (_Float16)a1[e]; }
            waf[kt] = f;
        }
        #pragma unroll
        for (int r = 0; r < 4; ++r) ba4[r] = ba[w * 16 + g * 4 + r];

        float cst[4] = {0.f, 0.f, 0.f, 0.f};
        __syncthreads();

        for (int t = 0; t < T_; ++t) {
            const int tb = t & 7;
            if (tb == 0) {
                const int c = t >> 3;
                if (tid == 0) fwait(&fh0[bg], c + 1);
                __syncthreads();
                // stage h0 ring slot -> xbuf via coherent 8B loads
                const _Float16* sbh = h0r + (size_t)(bg * RH + (c & (RH - 1))) * H0SLOT;
                const int pq = tid >> 2;
                const int b = pq >> 3, trow = pq & 7;
                const int u0 = (tid & 3) * 32;
                const _Float16* src = sbh + (trow * 16 + b) * 128 + u0;
                #pragma unroll
                for (int e = 0; e < 8; ++e) {
                    half4_ v = ld8(src + e * 4);
                    *(half4_*)&xbuf[trow][b][u0 + e * 4] = v;
                }
                lds_barrier();
                if (tid == 0) frel(&fs1[bg], c + 1);   // slot consumed
            }

            const int rd = (t ^ 1) & 1;
            const int wr = t & 1;

            f32x4 ai0 = bias[0], ai1 = bias[1], ai2 = bias[2], ai3 = bias[3];
            f32x4 ah0 = {0,0,0,0}, ah1 = {0,0,0,0}, ah2 = {0,0,0,0}, ah3 = {0,0,0,0};
            half8 hf[4];
            #pragma unroll
            for (int kt = 0; kt < 4; ++kt) {
                const int ko = kt * 32 + g * 8;
                const half8 xf = *(const half8*)&xbuf[tb][cl][ko];
                hf[kt]         = *(const half8*)&hbuf[rd][cl][ko];
                ai0 = MFMA16(wihf[0][kt], xf, ai0);
                ai1 = MFMA16(wihf[1][kt], xf, ai1);
                ai2 = MFMA16(wihf[2][kt], xf, ai2);
                ai3 = MFMA16(wihf[3][kt], xf, ai3);
                ah0 = MFMA16(whhf[0][kt], hf[kt], ah0);
                ah1 = MFMA16(whhf[1][kt], hf[kt], ah1);
                ah2 = MFMA16(whhf[2][kt], hf[kt], ah2);
                ah3 = MFMA16(whhf[3][kt], hf[kt], ah3);
            }

            if (t > 0) {   // head term for h1(t-1)
                f32x4 aacc = ba4;
                #pragma unroll
                for (int kt = 0; kt < 4; ++kt) aacc = MFMA16(waf[kt], hf[kt], aacc);
                #pragma unroll
                for (int r = 0; r < 4; ++r) {
                    const float a = aacc[r];
                    oacc[r] += a * fmaxf(a, 0.f);
                }
            }

            half4_ h4;
            #pragma unroll
            for (int r = 0; r < 4; ++r) {
                const float i_ = ai0[r] + ah0[r];
                const float f_ = ai1[r] + ah1[r];
                const float g_ = ai2[r] + ah2[r];
                const float o_ = ai3[r] + ah3[r];
                const float is = sigm_(i_);
                const float fs = sigm_(f_);
                const float gt_ = tanh_(g_);
                const float os = sigm_(o_);
                cst[r] = fs * cst[r] + is * gt_;
                h4[r] = (_Float16)(os * tanh_(cst[r]));
            }
            const int u0 = w * 16 + g * 4;
            *(half4_*)&hbuf[wr][cl][u0] = h4;
            lds_barrier();
        }

        // final head term for h1(T-1) in hbuf[1]
        f32x4 aacc = ba4;
        #pragma unroll
        for (int kt = 0; kt < 4; ++kt) {
            const half8 hfv = *(const half8*)&hbuf[1][cl][kt * 32 + g * 8];
            aacc = MFMA16(waf[kt], hfv, aacc);
        }
        #pragma unroll
        for (int r = 0; r < 4; ++r) {
            const float a = aacc[r];
            oacc[r] += a * fmaxf(a, 0.f);
        }
        *(f32x4*)&out[(size_t)(b0 + cl) * H_ + w * 16 + g * 4] = oacc;
    }
}

extern "C" void kernel_launch(void* const* d_in, const int* in_sizes, int n_in,
                              void* d_out, int out_size, void* d_ws, size_t ws_size,
                              hipStream_t stream) {
    const float* y    = (const float*)d_in[0];
    const float* Wih0 = (const float*)d_in[1];
    const float* Whh0 = (const float*)d_in[2];
    const float* bih0 = (const float*)d_in[3];
    const float* bhh0 = (const float*)d_in[4];
    const float* Wih1 = (const float*)d_in[5];
    const float* Whh1 = (const float*)d_in[6];
    const float* bih1 = (const float*)d_in[7];
    const float* bhh1 = (const float*)d_in[8];
    const float* Wa   = (const float*)d_in[9];
    const float* ba   = (const float*)d_in[10];
    float* out = (float*)d_out;

    const size_t SEED_BYTES = (size_t)NBG * RS * SEEDSLOT * 2;   // 16 MiB
    const size_t H0_BYTES   = (size_t)NBG * RH * H0SLOT * 2;     // 4 MiB
    char* p = (char*)d_ws;
    _Float16* seeds = (_Float16*)p;             p += SEED_BYTES;
    _Float16* h0r   = (_Float16*)p;             p += H0_BYTES;
    int*      flags = (int*)p;

    hipMemsetAsync(flags, 0, 512, stream);
    lstm3<<<3 * NBG, 512, 0, stream>>>(y, Wih0, Whh0, bih0, bhh0,
                                       Wih1, Whh1, bih1, bhh1, Wa, ba,
                                       seeds, h0r, flags, out);
}

// Round 19
// 751.773 us; speedup vs baseline: 3.8557x; 1.0391x over previous
//
#include <hip/hip_runtime.h>

// LSTMFeatureExtractor: 2-layer LSTM (H=128) over B=512, T=512, + a*relu(a) head.
// Round 19 = round-18 (best, 781us) + ONE mechanism: cross-chunk prefetch.
// Both chain stages hid their per-chunk serial prologue (flag RTT + L3 load
// latency + barrier, ~1500-2500cyc/chunk) inside the PREVIOUS chunk:
//  S0: step5 pre-waits flags; step6 loads chunk c+1's first seeds into regs
//      (sdn); chunk start = register copy, no wait/sync.
//  S1: xbuf double-buffered; step5 pre-waits fh0; step6 loads slot c+1 into
//      regs (pfv); step7 ds_writes them to xbuf[(c+1)&1]; chunk start = nothing.
//      fs1 credit released at chunk end (+prologue). Ring slack re-audited.
// Data still moves via relaxed agent atomics (sc0sc1, coherent L3) per r18.

typedef _Float16 half8  __attribute__((ext_vector_type(8)));
typedef _Float16 half4_ __attribute__((ext_vector_type(4)));
typedef float    f32x4  __attribute__((ext_vector_type(4)));

#define H_    128
#define T_    512
#define B_    512
#define BCH   16
#define NBG   32
#define NCH   64                  // 8-step chunks
#define KPAD  136
#define RS    4                   // seed ring depth
#define RH    4                   // h0 ring depth
#define SEEDSLOT (8 * 4 * 512 * 4)    // halves per (bg,slot): 65536 (128KB)
#define H0SLOT   (8 * 16 * 128)       // halves per (bg,slot): 16384 (32KB)

#define LOG2E 1.44269504089f

__device__ __forceinline__ float sigm_(float x) {
    return __builtin_amdgcn_rcpf(1.f + __builtin_amdgcn_exp2f(-LOG2E * x));
}
__device__ __forceinline__ float tanh_(float x) {
    return 1.f - 2.f * __builtin_amdgcn_rcpf(1.f + __builtin_amdgcn_exp2f((2.f * LOG2E) * x));
}
__device__ __forceinline__ void lds_barrier() {
    __builtin_amdgcn_sched_barrier(0);
    asm volatile("s_waitcnt lgkmcnt(0)" ::: "memory");
    __builtin_amdgcn_sched_barrier(0);
    __builtin_amdgcn_s_barrier();
    __builtin_amdgcn_sched_barrier(0);
}
// relaxed poll: no buffer_inv
__device__ __forceinline__ void fwait(const int* p, int tgt) {
    while (__hip_atomic_load(p, __ATOMIC_RELAXED, __HIP_MEMORY_SCOPE_AGENT) < tgt)
        __builtin_amdgcn_s_sleep(2);
}
// relaxed RMW release at coherence point (no wbl2); always after a barrier
// whose vmcnt(0) drained this block's sc0sc1 data stores.
__device__ __forceinline__ void frel(int* p, int v) {
    __hip_atomic_fetch_max(p, v, __ATOMIC_RELAXED, __HIP_MEMORY_SCOPE_AGENT);
}
// 8-byte coherent data movers (sc0 sc1, L3-served)
__device__ __forceinline__ void st8(_Float16* p, half4_ v) {
    unsigned long long u;
    __builtin_memcpy(&u, &v, 8);
    __hip_atomic_store((unsigned long long*)p, u, __ATOMIC_RELAXED,
                       __HIP_MEMORY_SCOPE_AGENT);
}
__device__ __forceinline__ half4_ ld8(const _Float16* p) {
    unsigned long long u =
        __hip_atomic_load((const unsigned long long*)p, __ATOMIC_RELAXED,
                          __HIP_MEMORY_SCOPE_AGENT);
    half4_ v;
    __builtin_memcpy(&v, &u, 8);
    return v;
}
__device__ __forceinline__ f32x4 cvt4(half4_ h) {
    return f32x4{(float)h[0], (float)h[1], (float)h[2], (float)h[3]};
}
__device__ __forceinline__ half4_ cvh4(f32x4 v) {
    return half4_{(_Float16)v[0], (_Float16)v[1], (_Float16)v[2], (_Float16)v[3]};
}

#define MFMA16(A, Bv, C) __builtin_amdgcn_mfma_f32_16x16x32_f16((A), (Bv), (C), 0, 0, 0)

__global__ void __launch_bounds__(512)
lstm3(const float* __restrict__ y,
      const float* __restrict__ Wih0, const float* __restrict__ Whh0,
      const float* __restrict__ bih0, const float* __restrict__ bhh0,
      const float* __restrict__ Wih1, const float* __restrict__ Whh1,
      const float* __restrict__ bih1, const float* __restrict__ bhh1,
      const float* __restrict__ Wa,  const float* __restrict__ ba,
      _Float16* __restrict__ seeds, _Float16* __restrict__ h0r,
      int* __restrict__ flags, float* __restrict__ out)
{
    __shared__ _Float16 xbuf[2][8][16][KPAD];   // P0 uses [0]; S1 double-buffers
    __shared__ _Float16 hbuf[2][16][KPAD];

    const int tid = threadIdx.x;
    const int w   = tid >> 6;
    const int l   = tid & 63;
    const int g   = l >> 4;
    const int cl  = l & 15;
    const int role = blockIdx.x % 3;     // 0=P0 1=S0 2=S1
    const int bg   = blockIdx.x / 3;
    const int b0   = bg * BCH;

    int* fg0 = flags;        // P0 -> S0: seeds chunk ready
    int* fs0 = flags + 32;   // S0 -> P0: seed slot credit
    int* fh0 = flags + 64;   // S0 -> S1: h0 chunk ready
    int* fs1 = flags + 96;   // S1 -> S0: h0 slot credit

    { // zero hbuf (initial h state for S roles)
        int* q = (int*)&hbuf[0][0][0];
        for (int i = tid; i < (int)(sizeof(hbuf) / 4); i += 512) q[i] = 0;
    }

    if (role == 0) {
        // ====================== P0: layer-0 input projection ======================
        half8 wf[4][4];
        #pragma unroll
        for (int gt = 0; gt < 4; ++gt) {
            const int grow = gt * 128 + w * 16 + cl;
            #pragma unroll
            for (int kt = 0; kt < 4; ++kt) {
                const float* pa = Wih0 + grow * H_ + kt * 32 + g * 8;
                f32x4 a0 = *(const f32x4*)(pa);
                f32x4 a1 = *(const f32x4*)(pa + 4);
                half8 fa;
                #pragma unroll
                for (int e = 0; e < 4; ++e) { fa[e] = (_Float16)a0[e]; fa[e + 4] = (_Float16)a1[e]; }
                wf[gt][kt] = fa;
            }
        }
        f32x4 bias[4];
        #pragma unroll
        for (int gt = 0; gt < 4; ++gt)
            #pragma unroll
            for (int r = 0; r < 4; ++r) {
                const int R = gt * 128 + w * 16 + g * 4 + r;
                bias[gt][r] = bih0[R] + bhh0[R];
            }
        __syncthreads();

        for (int c = 0; c < NCH; ++c) {
            if (tid == 0 && c >= RS) fwait(&fs0[bg], c - (RS - 1));
            __syncthreads();

            // stage y[b][k][c*8..+8) -> xbuf[0] (f16)
            #pragma unroll
            for (int rr = 0; rr < 4; ++rr) {
                const int q = tid + rr * 512;
                const int b = q >> 7, k = q & 127;
                const float* src = y + ((size_t)((b0 + b) * H_ + k)) * T_ + c * 8;
                f32x4 v0 = *(const f32x4*)(src);
                f32x4 v1 = *(const f32x4*)(src + 4);
                #pragma unroll
                for (int e = 0; e < 4; ++e) {
                    xbuf[0][e][b][k]     = (_Float16)v0[e];
                    xbuf[0][e + 4][b][k] = (_Float16)v1[e];
                }
            }
            lds_barrier();

            _Float16* sb = seeds + (size_t)(bg * RS + (c & (RS - 1))) * SEEDSLOT;
            for (int s = 0; s < 8; ++s) {
                half8 xf[4];
                #pragma unroll
                for (int kt = 0; kt < 4; ++kt)
                    xf[kt] = *(const half8*)&xbuf[0][s][cl][kt * 32 + g * 8];
                #pragma unroll
                for (int gt = 0; gt < 4; ++gt) {
                    f32x4 acc = bias[gt];
                    #pragma unroll
                    for (int kt = 0; kt < 4; ++kt)
                        acc = MFMA16(wf[gt][kt], xf[kt], acc);
                    st8(sb + ((size_t)(s * 4 + gt) * 512 + tid) * 4, cvh4(acc));
                }
            }
            __syncthreads();                 // drains all waves' sc0sc1 stores
            if (tid == 0) frel(&fg0[bg], c + 1);
        }
    } else if (role == 1) {
        // ====================== S0: light recurrence, layer 0 ======================
        half8 whh[4][4];
        #pragma unroll
        for (int gt = 0; gt < 4; ++gt) {
            const int grow = gt * 128 + w * 16 + cl;
            #pragma unroll
            for (int kt = 0; kt < 4; ++kt) {
                const float* pb = Whh0 + grow * H_ + kt * 32 + g * 8;
                f32x4 c0 = *(const f32x4*)(pb);
                f32x4 c1 = *(const f32x4*)(pb + 4);
                half8 fb;
                #pragma unroll
                for (int e = 0; e < 4; ++e) { fb[e] = (_Float16)c0[e]; fb[e + 4] = (_Float16)c1[e]; }
                whh[gt][kt] = fb;
            }
        }
        float cst[4] = {0.f, 0.f, 0.f, 0.f};
        half4_ sdn[2][4];                    // next-chunk seed prefetch regs
        __syncthreads();

        for (int c = 0; c < NCH; ++c) {
            const _Float16* sb = seeds + (size_t)(bg * RS + (c & (RS - 1))) * SEEDSLOT
                               + (size_t)tid * 4;
            _Float16* hb = h0r + (size_t)(bg * RH + (c & (RH - 1))) * H0SLOT;

            half4_ sd[2][4];
            if (c == 0) {
                if (tid == 0) fwait(&fg0[bg], 1);
                __syncthreads();
                #pragma unroll
                for (int gt = 0; gt < 4; ++gt)
                    sd[0][gt] = ld8(sb + (size_t)(0 * 4 + gt) * 2048);
                #pragma unroll
                for (int gt = 0; gt < 4; ++gt)
                    sd[1][gt] = ld8(sb + (size_t)(1 * 4 + gt) * 2048);
            } else {
                #pragma unroll
                for (int gt = 0; gt < 4; ++gt) { sd[0][gt] = sdn[0][gt]; sd[1][gt] = sdn[1][gt]; }
            }

            #pragma unroll
            for (int s = 0; s < 8; ++s) {
                const int rd = (s ^ 1) & 1;
                const int wr = s & 1;

                // cross-chunk seed prefetch (flags confirmed at s==5 of chunk c)
                if (s == 6 && c + 1 < NCH) {
                    const _Float16* sbn = seeds
                        + (size_t)(bg * RS + ((c + 1) & (RS - 1))) * SEEDSLOT
                        + (size_t)tid * 4;
                    #pragma unroll
                    for (int gt = 0; gt < 4; ++gt)
                        sdn[0][gt] = ld8(sbn + (size_t)(0 * 4 + gt) * 2048);
                    #pragma unroll
                    for (int gt = 0; gt < 4; ++gt)
                        sdn[1][gt] = ld8(sbn + (size_t)(1 * 4 + gt) * 2048);
                }

                half8 hf[4];
                #pragma unroll
                for (int kt = 0; kt < 4; ++kt)
                    hf[kt] = *(const half8*)&hbuf[rd][cl][kt * 32 + g * 8];

                f32x4 a0 = cvt4(sd[s & 1][0]);
                f32x4 a1 = cvt4(sd[s & 1][1]);
                f32x4 a2 = cvt4(sd[s & 1][2]);
                f32x4 a3 = cvt4(sd[s & 1][3]);
                if (s + 2 < 8) {
                    #pragma unroll
                    for (int gt = 0; gt < 4; ++gt)
                        sd[s & 1][gt] = ld8(sb + (size_t)((s + 2) * 4 + gt) * 2048);
                }

                #pragma unroll
                for (int kt = 0; kt < 4; ++kt) {
                    a0 = MFMA16(whh[0][kt], hf[kt], a0);
                    a1 = MFMA16(whh[1][kt], hf[kt], a1);
                    a2 = MFMA16(whh[2][kt], hf[kt], a2);
                    a3 = MFMA16(whh[3][kt], hf[kt], a3);
                }

                half4_ h4;
                #pragma unroll
                for (int r = 0; r < 4; ++r) {
                    const float is  = sigm_(a0[r]);
                    const float fs  = sigm_(a1[r]);
                    const float gt_ = tanh_(a2[r]);
                    const float os  = sigm_(a3[r]);
                    cst[r] = fs * cst[r] + is * gt_;
                    h4[r] = (_Float16)(os * tanh_(cst[r]));
                }
                const int u0 = w * 16 + g * 4;
                *(half4_*)&hbuf[wr][cl][u0] = h4;
                st8(hb + (s * 16 + cl) * 128 + u0, h4);   // coherent h0 store

                // pre-wait next chunk's flags off-chain (replaces chunk-start wait)
                if (s == 5 && tid == 0 && c + 1 < NCH) {
                    fwait(&fg0[bg], c + 2);
                    if (c + 1 >= RH) fwait(&fs1[bg], (c + 1) - (RH - 1));
                }

                if (s < 7) {
                    lds_barrier();
                } else {
                    __syncthreads();            // drains h0 stores + seed loads
                    if (tid == 0) {
                        frel(&fh0[bg], c + 1);  // h0 chunk ready for S1
                        frel(&fs0[bg], c + 1);  // seed slot free for P0
                    }
                }
            }
        }
    } else {
        // ====================== S1: layer-1 recurrence + head ======================
        half8 wihf[4][4], whhf[4][4];
        #pragma unroll
        for (int gt = 0; gt < 4; ++gt) {
            const int grow = gt * 128 + w * 16 + cl;
            #pragma unroll
            for (int kt = 0; kt < 4; ++kt) {
                const float* pa = Wih1 + grow * H_ + kt * 32 + g * 8;
                const float* pb = Whh1 + grow * H_ + kt * 32 + g * 8;
                f32x4 a0 = *(const f32x4*)(pa);
                f32x4 a1 = *(const f32x4*)(pa + 4);
                f32x4 c0 = *(const f32x4*)(pb);
                f32x4 c1 = *(const f32x4*)(pb + 4);
                half8 fa, fb;
                #pragma unroll
                for (int e = 0; e < 4; ++e) {
                    fa[e] = (_Float16)a0[e]; fa[e + 4] = (_Float16)a1[e];
                    fb[e] = (_Float16)c0[e]; fb[e + 4] = (_Float16)c1[e];
                }
                wihf[gt][kt] = fa; whhf[gt][kt] = fb;
            }
        }
        f32x4 bias[4];
        #pragma unroll
        for (int gt = 0; gt < 4; ++gt)
            #pragma unroll
            for (int r = 0; r < 4; ++r) {
                const int R = gt * 128 + w * 16 + g * 4 + r;
                bias[gt][r] = bih1[R] + bhh1[R];
            }
        half8 waf[4];
        f32x4 ba4  = {0.f, 0.f, 0.f, 0.f};
        f32x4 oacc = {0.f, 0.f, 0.f, 0.f};
        #pragma unroll
        for (int kt = 0; kt < 4; ++kt) {
            const float* p = Wa + (w * 16 + cl) * H_ + kt * 32 + g * 8;
            f32x4 a0 = *(const f32x4*)(p);
            f32x4 a1 = *(const f32x4*)(p + 4);
            half8 f;
            #pragma unroll
            for (int e = 0; e < 4; ++e) { f[e] = (_Float16)a0[e]; f[e + 4] = (_Float16)a1[e]; }
            waf[kt] = f;
        }
        #pragma unroll
        for (int r = 0; r < 4; ++r) ba4[r] = ba[w * 16 + g * 4 + r];

        float cst[4] = {0.f, 0.f, 0.f, 0.f};

        // staging thread-geometry (per-thread-contiguous 64B of one (trow,b) row)
        const int pq_   = tid >> 2;
        const int sb_   = pq_ >> 3;
        const int strow = pq_ & 7;
        const int su0   = (tid & 3) * 32;

        __syncthreads();

        // prologue: stage h0 slot 0 -> xbuf[0]
        if (tid == 0) fwait(&fh0[bg], 1);
        __syncthreads();
        {
            const _Float16* src0 = h0r + (size_t)(bg * RH + 0) * H0SLOT
                                 + (strow * 16 + sb_) * 128 + su0;
            #pragma unroll
            for (int e = 0; e < 8; ++e) {
                half4_ v = ld8(src0 + e * 4);
                *(half4_*)&xbuf[0][strow][sb_][su0 + e * 4] = v;
            }
        }
        lds_barrier();
        if (tid == 0) frel(&fs1[bg], 1);   // slot 0 consumed

        half4_ pfv[8];                     // next-slot prefetch regs
        for (int t = 0; t < T_; ++t) {
            const int tb = t & 7;
            const int c  = t >> 3;

            // step 6: issue coherent loads of slot c+1 (flag confirmed at tb==5)
            if (tb == 6 && c + 1 < NCH) {
                const _Float16* srcn = h0r
                    + (size_t)(bg * RH + ((c + 1) & (RH - 1))) * H0SLOT
                    + (strow * 16 + sb_) * 128 + su0;
                #pragma unroll
                for (int e = 0; e < 8; ++e) pfv[e] = ld8(srcn + e * 4);
            }
            // step 7: write them to the other xbuf half (drained by this step's barrier)
            if (tb == 7 && c + 1 < NCH) {
                #pragma unroll
                for (int e = 0; e < 8; ++e)
                    *(half4_*)&xbuf[(c + 1) & 1][strow][sb_][su0 + e * 4] = pfv[e];
            }

            const int rd = (t ^ 1) & 1;
            const int wr = t & 1;

            f32x4 ai0 = bias[0], ai1 = bias[1], ai2 = bias[2], ai3 = bias[3];
            f32x4 ah0 = {0,0,0,0}, ah1 = {0,0,0,0}, ah2 = {0,0,0,0}, ah3 = {0,0,0,0};
            half8 hf[4];
            #pragma unroll
            for (int kt = 0; kt < 4; ++kt) {
                const int ko = kt * 32 + g * 8;
                const half8 xf = *(const half8*)&xbuf[c & 1][tb][cl][ko];
                hf[kt]         = *(const half8*)&hbuf[rd][cl][ko];
                ai0 = MFMA16(wihf[0][kt], xf, ai0);
                ai1 = MFMA16(wihf[1][kt], xf, ai1);
                ai2 = MFMA16(wihf[2][kt], xf, ai2);
                ai3 = MFMA16(wihf[3][kt], xf, ai3);
                ah0 = MFMA16(whhf[0][kt], hf[kt], ah0);
                ah1 = MFMA16(whhf[1][kt], hf[kt], ah1);
                ah2 = MFMA16(whhf[2][kt], hf[kt], ah2);
                ah3 = MFMA16(whhf[3][kt], hf[kt], ah3);
            }

            if (t > 0) {   // head term for h1(t-1)
                f32x4 aacc = ba4;
                #pragma unroll
                for (int kt = 0; kt < 4; ++kt) aacc = MFMA16(waf[kt], hf[kt], aacc);
                #pragma unroll
                for (int r = 0; r < 4; ++r) {
                    const float a = aacc[r];
                    oacc[r] += a * fmaxf(a, 0.f);
                }
            }

            half4_ h4;
            #pragma unroll
            for (int r = 0; r < 4; ++r) {
                const float i_ = ai0[r] + ah0[r];
                const float f_ = ai1[r] + ah1[r];
                const float g_ = ai2[r] + ah2[r];
                const float o_ = ai3[r] + ah3[r];
                const float is = sigm_(i_);
                const float fs = sigm_(f_);
                const float gt_ = tanh_(g_);
                const float os = sigm_(o_);
                cst[r] = fs * cst[r] + is * gt_;
                h4[r] = (_Float16)(os * tanh_(cst[r]));
            }
            const int u0 = w * 16 + g * 4;
            *(half4_*)&hbuf[wr][cl][u0] = h4;

            // pre-wait next chunk's h0 flag off-chain
            if (tb == 5 && tid == 0 && c + 1 < NCH) fwait(&fh0[bg], c + 2);

            lds_barrier();
            if (tb == 7 && tid == 0 && c + 1 < NCH)
                frel(&fs1[bg], c + 2);   // slot c+1 consumed (prefetch loads retired)
        }

        // final head term for h1(T-1) in hbuf[1]
        f32x4 aacc = ba4;
        #pragma unroll
        for (int kt = 0; kt < 4; ++kt) {
            const half8 hfv = *(const half8*)&hbuf[1][cl][kt * 32 + g * 8];
            aacc = MFMA16(waf[kt], hfv, aacc);
        }
        #pragma unroll
        for (int r = 0; r < 4; ++r) {
            const float a = aacc[r];
            oacc[r] += a * fmaxf(a, 0.f);
        }
        *(f32x4*)&out[(size_t)(b0 + cl) * H_ + w * 16 + g * 4] = oacc;
    }
}

extern "C" void kernel_launch(void* const* d_in, const int* in_sizes, int n_in,
                              void* d_out, int out_size, void* d_ws, size_t ws_size,
                              hipStream_t stream) {
    const float* y    = (const float*)d_in[0];
    const float* Wih0 = (const float*)d_in[1];
    const float* Whh0 = (const float*)d_in[2];
    const float* bih0 = (const float*)d_in[3];
    const float* bhh0 = (const float*)d_in[4];
    const float* Wih1 = (const float*)d_in[5];
    const float* Whh1 = (const float*)d_in[6];
    const float* bih1 = (const float*)d_in[7];
    const float* bhh1 = (const float*)d_in[8];
    const float* Wa   = (const float*)d_in[9];
    const float* ba   = (const float*)d_in[10];
    float* out = (float*)d_out;

    const size_t SEED_BYTES = (size_t)NBG * RS * SEEDSLOT * 2;   // 16 MiB
    const size_t H0_BYTES   = (size_t)NBG * RH * H0SLOT * 2;     // 4 MiB
    char* p = (char*)d_ws;
    _Float16* seeds = (_Float16*)p;             p += SEED_BYTES;
    _Float16* h0r   = (_Float16*)p;             p += H0_BYTES;
    int*      flags = (int*)p;

    hipMemsetAsync(flags, 0, 512, stream);
    lstm3<<<3 * NBG, 512, 0, stream>>>(y, Wih0, Whh0, bih0, bhh0,
                                       Wih1, Whh1, bih1, bhh1, Wa, ba,
                                       seeds, h0r, flags, out);
}

// Round 20
// 533.706 us; speedup vs baseline: 5.4310x; 1.4086x over previous
//
#include <hip/hip_runtime.h>

// LSTMFeatureExtractor: 2-layer LSTM (H=128) over B=512, T=512, + a*relu(a) head.
// Round 20 = r16's 4-role pipeline REBUILT with r18+r19 mechanics:
//  P0: seeds0 = bias0 + x@Wih0^T -> 4-deep ring (coherent st8, per-thread order)
//  S0: light rec-0 (16 hh-MFMAs, reg-prefetched seeds, cross-chunk prefetch),
//      h -> h0 ring via coherent st8. Credit for h0 slots comes from P1 staging.
//  P1: stage h0(c) (coherent ld8) -> release slot -> seeds1 = bias1 + Wih1*h0
//      -> ring (coherent st8).
//  S1: LIGHT rec-1 + head: 16 hh + 4 head MFMAs, reg-prefetched seeds1,
//      cross-chunk prefetch, nonlin, a*relu(a) -> out. (No xbuf, 4 ds_reads.)
// All handoffs: relaxed agent atomics (sc0sc1, coherent L3) + relaxed fetch_max
// flags after vmcnt-draining barriers (r18). All chunk prologues hidden via
// s==5 pre-wait + s==6 register prefetch (r19). Rings depth 4. DAG audited:
// S0(c)<-{P0(c),P1(c-4)}; P1(c)<-{S0(c),S1(c-4)}; S1(c)<-P1(c); P0(c)<-S0(c-4).

typedef _Float16 half8  __attribute__((ext_vector_type(8)));
typedef _Float16 half4_ __attribute__((ext_vector_type(4)));
typedef float    f32x4  __attribute__((ext_vector_type(4)));

#define H_    128
#define T_    512
#define B_    512
#define BCH   16
#define NBG   32
#define NCH   64                  // 8-step chunks
#define KPAD  136
#define RS    4                   // all ring depths
#define RH    4
#define SEEDSLOT (8 * 4 * 512 * 4)    // halves per (bg,slot): 65536 (128KB)
#define H0SLOT   (8 * 16 * 128)       // halves per (bg,slot): 16384 (32KB)

#define LOG2E 1.44269504089f

__device__ __forceinline__ float sigm_(float x) {
    return __builtin_amdgcn_rcpf(1.f + __builtin_amdgcn_exp2f(-LOG2E * x));
}
__device__ __forceinline__ float tanh_(float x) {
    return 1.f - 2.f * __builtin_amdgcn_rcpf(1.f + __builtin_amdgcn_exp2f((2.f * LOG2E) * x));
}
__device__ __forceinline__ void lds_barrier() {
    __builtin_amdgcn_sched_barrier(0);
    asm volatile("s_waitcnt lgkmcnt(0)" ::: "memory");
    __builtin_amdgcn_sched_barrier(0);
    __builtin_amdgcn_s_barrier();
    __builtin_amdgcn_sched_barrier(0);
}
__device__ __forceinline__ void fwait(const int* p, int tgt) {
    while (__hip_atomic_load(p, __ATOMIC_RELAXED, __HIP_MEMORY_SCOPE_AGENT) < tgt)
        __builtin_amdgcn_s_sleep(2);
}
__device__ __forceinline__ void frel(int* p, int v) {
    __hip_atomic_fetch_max(p, v, __ATOMIC_RELAXED, __HIP_MEMORY_SCOPE_AGENT);
}
__device__ __forceinline__ void st8(_Float16* p, half4_ v) {
    unsigned long long u;
    __builtin_memcpy(&u, &v, 8);
    __hip_atomic_store((unsigned long long*)p, u, __ATOMIC_RELAXED,
                       __HIP_MEMORY_SCOPE_AGENT);
}
__device__ __forceinline__ half4_ ld8(const _Float16* p) {
    unsigned long long u =
        __hip_atomic_load((const unsigned long long*)p, __ATOMIC_RELAXED,
                          __HIP_MEMORY_SCOPE_AGENT);
    half4_ v;
    __builtin_memcpy(&v, &u, 8);
    return v;
}
__device__ __forceinline__ f32x4 cvt4(half4_ h) {
    return f32x4{(float)h[0], (float)h[1], (float)h[2], (float)h[3]};
}
__device__ __forceinline__ half4_ cvh4(f32x4 v) {
    return half4_{(_Float16)v[0], (_Float16)v[1], (_Float16)v[2], (_Float16)v[3]};
}

#define MFMA16(A, Bv, C) __builtin_amdgcn_mfma_f32_16x16x32_f16((A), (Bv), (C), 0, 0, 0)

__global__ void __launch_bounds__(512)
lstm4(const float* __restrict__ y,
      const float* __restrict__ Wih0, const float* __restrict__ Whh0,
      const float* __restrict__ bih0, const float* __restrict__ bhh0,
      const float* __restrict__ Wih1, const float* __restrict__ Whh1,
      const float* __restrict__ bih1, const float* __restrict__ bhh1,
      const float* __restrict__ Wa,  const float* __restrict__ ba,
      _Float16* __restrict__ seeds0, _Float16* __restrict__ seeds1,
      _Float16* __restrict__ h0r,
      int* __restrict__ flags, float* __restrict__ out)
{
    __shared__ _Float16 xbuf[8][16][KPAD];   // P0/P1 staging
    __shared__ _Float16 hbuf[2][16][KPAD];   // S0/S1 h state

    const int tid = threadIdx.x;
    const int w   = tid >> 6;
    const int l   = tid & 63;
    const int g   = l >> 4;
    const int cl  = l & 15;
    const int role = blockIdx.x & 3;     // 0=P0 1=S0 2=P1 3=S1
    const int bg   = blockIdx.x >> 2;
    const int b0   = bg * BCH;

    int* fg0 = flags;         // P0 -> S0: seeds0 ready
    int* fs0 = flags + 32;    // S0 -> P0: seeds0 slot credit
    int* fh0 = flags + 64;    // S0 -> P1: h0 chunk ready
    int* fp1 = flags + 96;    // P1 -> S0: h0 slot credit (after staging)
    int* fg1 = flags + 128;   // P1 -> S1: seeds1 ready
    int* fs1 = flags + 160;   // S1 -> P1: seeds1 slot credit

    { // zero hbuf (initial h state for S roles)
        int* q = (int*)&hbuf[0][0][0];
        for (int i = tid; i < (int)(sizeof(hbuf) / 4); i += 512) q[i] = 0;
    }

    if (role == 0) {
        // ====================== P0: layer-0 input projection ======================
        half8 wf[4][4];
        #pragma unroll
        for (int gt = 0; gt < 4; ++gt) {
            const int grow = gt * 128 + w * 16 + cl;
            #pragma unroll
            for (int kt = 0; kt < 4; ++kt) {
                const float* pa = Wih0 + grow * H_ + kt * 32 + g * 8;
                f32x4 a0 = *(const f32x4*)(pa);
                f32x4 a1 = *(const f32x4*)(pa + 4);
                half8 fa;
                #pragma unroll
                for (int e = 0; e < 4; ++e) { fa[e] = (_Float16)a0[e]; fa[e + 4] = (_Float16)a1[e]; }
                wf[gt][kt] = fa;
            }
        }
        f32x4 bias[4];
        #pragma unroll
        for (int gt = 0; gt < 4; ++gt)
            #pragma unroll
            for (int r = 0; r < 4; ++r) {
                const int R = gt * 128 + w * 16 + g * 4 + r;
                bias[gt][r] = bih0[R] + bhh0[R];
            }
        __syncthreads();

        for (int c = 0; c < NCH; ++c) {
            if (tid == 0 && c >= RS) fwait(&fs0[bg], c - (RS - 1));
            __syncthreads();

            // stage y[b][k][c*8..+8) -> xbuf (f16)
            #pragma unroll
            for (int rr = 0; rr < 4; ++rr) {
                const int q = tid + rr * 512;
                const int b = q >> 7, k = q & 127;
                const float* src = y + ((size_t)((b0 + b) * H_ + k)) * T_ + c * 8;
                f32x4 v0 = *(const f32x4*)(src);
                f32x4 v1 = *(const f32x4*)(src + 4);
                #pragma unroll
                for (int e = 0; e < 4; ++e) {
                    xbuf[e][b][k]     = (_Float16)v0[e];
                    xbuf[e + 4][b][k] = (_Float16)v1[e];
                }
            }
            lds_barrier();

            _Float16* sb = seeds0 + (size_t)(bg * RS + (c & (RS - 1))) * SEEDSLOT;
            for (int s = 0; s < 8; ++s) {
                half8 xf[4];
                #pragma unroll
                for (int kt = 0; kt < 4; ++kt)
                    xf[kt] = *(const half8*)&xbuf[s][cl][kt * 32 + g * 8];
                #pragma unroll
                for (int gt = 0; gt < 4; ++gt) {
                    f32x4 acc = bias[gt];
                    #pragma unroll
                    for (int kt = 0; kt < 4; ++kt)
                        acc = MFMA16(wf[gt][kt], xf[kt], acc);
                    st8(sb + ((size_t)(s * 4 + gt) * 512 + tid) * 4, cvh4(acc));
                }
            }
            __syncthreads();                 // drains sc0sc1 stores (vmcnt)
            if (tid == 0) frel(&fg0[bg], c + 1);
        }
    } else if (role == 1) {
        // ====================== S0: light recurrence, layer 0 ======================
        half8 whh[4][4];
        #pragma unroll
        for (int gt = 0; gt < 4; ++gt) {
            const int grow = gt * 128 + w * 16 + cl;
            #pragma unroll
            for (int kt = 0; kt < 4; ++kt) {
                const float* pb = Whh0 + grow * H_ + kt * 32 + g * 8;
                f32x4 c0 = *(const f32x4*)(pb);
                f32x4 c1 = *(const f32x4*)(pb + 4);
                half8 fb;
                #pragma unroll
                for (int e = 0; e < 4; ++e) { fb[e] = (_Float16)c0[e]; fb[e + 4] = (_Float16)c1[e]; }
                whh[gt][kt] = fb;
            }
        }
        float cst[4] = {0.f, 0.f, 0.f, 0.f};
        half4_ sdn[2][4];
        __syncthreads();

        for (int c = 0; c < NCH; ++c) {
            const _Float16* sb = seeds0 + (size_t)(bg * RS + (c & (RS - 1))) * SEEDSLOT
                               + (size_t)tid * 4;
            _Float16* hb = h0r + (size_t)(bg * RH + (c & (RH - 1))) * H0SLOT;

            half4_ sd[2][4];
            if (c == 0) {
                if (tid == 0) fwait(&fg0[bg], 1);
                __syncthreads();
                #pragma unroll
                for (int gt = 0; gt < 4; ++gt)
                    sd[0][gt] = ld8(sb + (size_t)(0 * 4 + gt) * 2048);
                #pragma unroll
                for (int gt = 0; gt < 4; ++gt)
                    sd[1][gt] = ld8(sb + (size_t)(1 * 4 + gt) * 2048);
            } else {
                #pragma unroll
                for (int gt = 0; gt < 4; ++gt) { sd[0][gt] = sdn[0][gt]; sd[1][gt] = sdn[1][gt]; }
            }

            #pragma unroll
            for (int s = 0; s < 8; ++s) {
                const int rd = (s ^ 1) & 1;
                const int wr = s & 1;

                if (s == 6 && c + 1 < NCH) {    // cross-chunk seed prefetch
                    const _Float16* sbn = seeds0
                        + (size_t)(bg * RS + ((c + 1) & (RS - 1))) * SEEDSLOT
                        + (size_t)tid * 4;
                    #pragma unroll
                    for (int gt = 0; gt < 4; ++gt)
                        sdn[0][gt] = ld8(sbn + (size_t)(0 * 4 + gt) * 2048);
                    #pragma unroll
                    for (int gt = 0; gt < 4; ++gt)
                        sdn[1][gt] = ld8(sbn + (size_t)(1 * 4 + gt) * 2048);
                }

                half8 hf[4];
                #pragma unroll
                for (int kt = 0; kt < 4; ++kt)
                    hf[kt] = *(const half8*)&hbuf[rd][cl][kt * 32 + g * 8];

                f32x4 a0 = cvt4(sd[s & 1][0]);
                f32x4 a1 = cvt4(sd[s & 1][1]);
                f32x4 a2 = cvt4(sd[s & 1][2]);
                f32x4 a3 = cvt4(sd[s & 1][3]);
                if (s + 2 < 8) {
                    #pragma unroll
                    for (int gt = 0; gt < 4; ++gt)
                        sd[s & 1][gt] = ld8(sb + (size_t)((s + 2) * 4 + gt) * 2048);
                }

                #pragma unroll
                for (int kt = 0; kt < 4; ++kt) {
                    a0 = MFMA16(whh[0][kt], hf[kt], a0);
                    a1 = MFMA16(whh[1][kt], hf[kt], a1);
                    a2 = MFMA16(whh[2][kt], hf[kt], a2);
                    a3 = MFMA16(whh[3][kt], hf[kt], a3);
                }

                half4_ h4;
                #pragma unroll
                for (int r = 0; r < 4; ++r) {
                    const float is  = sigm_(a0[r]);
                    const float fs  = sigm_(a1[r]);
                    const float gt_ = tanh_(a2[r]);
                    const float os  = sigm_(a3[r]);
                    cst[r] = fs * cst[r] + is * gt_;
                    h4[r] = (_Float16)(os * tanh_(cst[r]));
                }
                const int u0 = w * 16 + g * 4;
                *(half4_*)&hbuf[wr][cl][u0] = h4;
                st8(hb + (s * 16 + cl) * 128 + u0, h4);   // coherent h0 store

                // pre-wait next chunk's flags (off-chain; propagated by barrier)
                if (s == 5 && tid == 0 && c + 1 < NCH) {
                    fwait(&fg0[bg], c + 2);
                    if (c + 1 >= RH) fwait(&fp1[bg], (c + 1) - (RH - 1));
                }

                if (s < 7) {
                    lds_barrier();
                } else {
                    __syncthreads();            // drains h0 stores + seed loads
                    if (tid == 0) {
                        frel(&fh0[bg], c + 1);  // h0 ready for P1
                        frel(&fs0[bg], c + 1);  // seeds0 slot free for P0
                    }
                }
            }
        }
    } else if (role == 2) {
        // ====================== P1: layer-1 input projection ======================
        half8 wf[4][4];
        #pragma unroll
        for (int gt = 0; gt < 4; ++gt) {
            const int grow = gt * 128 + w * 16 + cl;
            #pragma unroll
            for (int kt = 0; kt < 4; ++kt) {
                const float* pa = Wih1 + grow * H_ + kt * 32 + g * 8;
                f32x4 a0 = *(const f32x4*)(pa);
                f32x4 a1 = *(const f32x4*)(pa + 4);
                half8 fa;
                #pragma unroll
                for (int e = 0; e < 4; ++e) { fa[e] = (_Float16)a0[e]; fa[e + 4] = (_Float16)a1[e]; }
                wf[gt][kt] = fa;
            }
        }
        f32x4 bias[4];
        #pragma unroll
        for (int gt = 0; gt < 4; ++gt)
            #pragma unroll
            for (int r = 0; r < 4; ++r) {
                const int R = gt * 128 + w * 16 + g * 4 + r;
                bias[gt][r] = bih1[R] + bhh1[R];
            }
        // staging thread geometry (per-thread-contiguous 64B)
        const int pq_   = tid >> 2;
        const int sb_   = pq_ >> 3;
        const int strow = pq_ & 7;
        const int su0   = (tid & 3) * 32;
        __syncthreads();

        for (int c = 0; c < NCH; ++c) {
            if (tid == 0) {
                fwait(&fh0[bg], c + 1);                       // h0(c) ready
                if (c >= RS) fwait(&fs1[bg], c - (RS - 1));   // seeds1 slot free
            }
            __syncthreads();

            {   // stage h0 slot c -> xbuf via coherent ld8
                const _Float16* src = h0r + (size_t)(bg * RH + (c & (RH - 1))) * H0SLOT
                                    + (strow * 16 + sb_) * 128 + su0;
                #pragma unroll
                for (int e = 0; e < 8; ++e) {
                    half4_ v = ld8(src + e * 4);
                    *(half4_*)&xbuf[strow][sb_][su0 + e * 4] = v;
                }
            }
            lds_barrier();              // ds_writes done => src loads retired
            if (tid == 0) frel(&fp1[bg], c + 1);   // h0 slot free for S0

            _Float16* sbm = seeds1 + (size_t)(bg * RS + (c & (RS - 1))) * SEEDSLOT;
            for (int s = 0; s < 8; ++s) {
                half8 xf[4];
                #pragma unroll
                for (int kt = 0; kt < 4; ++kt)
                    xf[kt] = *(const half8*)&xbuf[s][cl][kt * 32 + g * 8];
                #pragma unroll
                for (int gt = 0; gt < 4; ++gt) {
                    f32x4 acc = bias[gt];
                    #pragma unroll
                    for (int kt = 0; kt < 4; ++kt)
                        acc = MFMA16(wf[gt][kt], xf[kt], acc);
                    st8(sbm + ((size_t)(s * 4 + gt) * 512 + tid) * 4, cvh4(acc));
                }
            }
            __syncthreads();                 // drains seeds1 stores + xbuf reads
            if (tid == 0) frel(&fg1[bg], c + 1);
        }
    } else {
        // ============ S1: light layer-1 recurrence + head ============
        half8 whh[4][4];
        #pragma unroll
        for (int gt = 0; gt < 4; ++gt) {
            const int grow = gt * 128 + w * 16 + cl;
            #pragma unroll
            for (int kt = 0; kt < 4; ++kt) {
                const float* pb = Whh1 + grow * H_ + kt * 32 + g * 8;
                f32x4 c0 = *(const f32x4*)(pb);
                f32x4 c1 = *(const f32x4*)(pb + 4);
                half8 fb;
                #pragma unroll
                for (int e = 0; e < 4; ++e) { fb[e] = (_Float16)c0[e]; fb[e + 4] = (_Float16)c1[e]; }
                whh[gt][kt] = fb;
            }
        }
        half8 waf[4];
        f32x4 ba4  = {0.f, 0.f, 0.f, 0.f};
        f32x4 oacc = {0.f, 0.f, 0.f, 0.f};
        #pragma unroll
        for (int kt = 0; kt < 4; ++kt) {
            const float* p = Wa + (w * 16 + cl) * H_ + kt * 32 + g * 8;
            f32x4 a0 = *(const f32x4*)(p);
            f32x4 a1 = *(const f32x4*)(p + 4);
            half8 f;
            #pragma unroll
            for (int e = 0; e < 4; ++e) { f[e] = (_Float16)a0[e]; f[e + 4] = (_Float16)a1[e]; }
            waf[kt] = f;
        }
        #pragma unroll
        for (int r = 0; r < 4; ++r) ba4[r] = ba[w * 16 + g * 4 + r];

        float cst[4] = {0.f, 0.f, 0.f, 0.f};
        half4_ sdn[2][4];
        __syncthreads();

        for (int c = 0; c < NCH; ++c) {
            const _Float16* sb = seeds1 + (size_t)(bg * RS + (c & (RS - 1))) * SEEDSLOT
                               + (size_t)tid * 4;
            half4_ sd[2][4];
            if (c == 0) {
                if (tid == 0) fwait(&fg1[bg], 1);
                __syncthreads();
                #pragma unroll
                for (int gt = 0; gt < 4; ++gt)
                    sd[0][gt] = ld8(sb + (size_t)(0 * 4 + gt) * 2048);
                #pragma unroll
                for (int gt = 0; gt < 4; ++gt)
                    sd[1][gt] = ld8(sb + (size_t)(1 * 4 + gt) * 2048);
            } else {
                #pragma unroll
                for (int gt = 0; gt < 4; ++gt) { sd[0][gt] = sdn[0][gt]; sd[1][gt] = sdn[1][gt]; }
            }

            #pragma unroll
            for (int s = 0; s < 8; ++s) {
                const int t  = c * 8 + s;
                const int rd = (s ^ 1) & 1;
                const int wr = s & 1;

                if (s == 6 && c + 1 < NCH) {    // cross-chunk seed prefetch
                    const _Float16* sbn = seeds1
                        + (size_t)(bg * RS + ((c + 1) & (RS - 1))) * SEEDSLOT
                        + (size_t)tid * 4;
                    #pragma unroll
                    for (int gt = 0; gt < 4; ++gt)
                        sdn[0][gt] = ld8(sbn + (size_t)(0 * 4 + gt) * 2048);
                    #pragma unroll
                    for (int gt = 0; gt < 4; ++gt)
                        sdn[1][gt] = ld8(sbn + (size_t)(1 * 4 + gt) * 2048);
                }

                half8 hf[4];       // h1(t-1)
                #pragma unroll
                for (int kt = 0; kt < 4; ++kt)
                    hf[kt] = *(const half8*)&hbuf[rd][cl][kt * 32 + g * 8];

                f32x4 a0 = cvt4(sd[s & 1][0]);
                f32x4 a1 = cvt4(sd[s & 1][1]);
                f32x4 a2 = cvt4(sd[s & 1][2]);
                f32x4 a3 = cvt4(sd[s & 1][3]);
                if (s + 2 < 8) {
                    #pragma unroll
                    for (int gt = 0; gt < 4; ++gt)
                        sd[s & 1][gt] = ld8(sb + (size_t)((s + 2) * 4 + gt) * 2048);
                }
                #pragma unroll
                for (int kt = 0; kt < 4; ++kt) {
                    a0 = MFMA16(whh[0][kt], hf[kt], a0);
                    a1 = MFMA16(whh[1][kt], hf[kt], a1);
                    a2 = MFMA16(whh[2][kt], hf[kt], a2);
                    a3 = MFMA16(whh[3][kt], hf[kt], a3);
                }

                if (t > 0) {     // head term for h1(t-1)
                    f32x4 aacc = ba4;
                    #pragma unroll
                    for (int kt = 0; kt < 4; ++kt) aacc = MFMA16(waf[kt], hf[kt], aacc);
                    #pragma unroll
                    for (int r = 0; r < 4; ++r) {
                        const float a = aacc[r];
                        oacc[r] += a * fmaxf(a, 0.f);
                    }
                }

                half4_ h4;
                #pragma unroll
                for (int r = 0; r < 4; ++r) {
                    const float is  = sigm_(a0[r]);
                    const float fs  = sigm_(a1[r]);
                    const float gt_ = tanh_(a2[r]);
                    const float os  = sigm_(a3[r]);
                    cst[r] = fs * cst[r] + is * gt_;
                    h4[r] = (_Float16)(os * tanh_(cst[r]));
                }
                const int u0 = w * 16 + g * 4;
                *(half4_*)&hbuf[wr][cl][u0] = h4;

                if (s == 5 && tid == 0 && c + 1 < NCH) fwait(&fg1[bg], c + 2);

                if (s < 7) {
                    lds_barrier();
                } else {
                    __syncthreads();               // seeds1 reads retired
                    if (tid == 0) frel(&fs1[bg], c + 1);
                }
            }
        }

        // final head term for h1(T-1) in hbuf[1]
        f32x4 aacc = ba4;
        #pragma unroll
        for (int kt = 0; kt < 4; ++kt) {
            const half8 hfv = *(const half8*)&hbuf[1][cl][kt * 32 + g * 8];
            aacc = MFMA16(waf[kt], hfv, aacc);
        }
        #pragma unroll
        for (int r = 0; r < 4; ++r) {
            const float a = aacc[r];
            oacc[r] += a * fmaxf(a, 0.f);
        }
        *(f32x4*)&out[(size_t)(b0 + cl) * H_ + w * 16 + g * 4] = oacc;
    }
}

extern "C" void kernel_launch(void* const* d_in, const int* in_sizes, int n_in,
                              void* d_out, int out_size, void* d_ws, size_t ws_size,
                              hipStream_t stream) {
    const float* y    = (const float*)d_in[0];
    const float* Wih0 = (const float*)d_in[1];
    const float* Whh0 = (const float*)d_in[2];
    const float* bih0 = (const float*)d_in[3];
    const float* bhh0 = (const float*)d_in[4];
    const float* Wih1 = (const float*)d_in[5];
    const float* Whh1 = (const float*)d_in[6];
    const float* bih1 = (const float*)d_in[7];
    const float* bhh1 = (const float*)d_in[8];
    const float* Wa   = (const float*)d_in[9];
    const float* ba   = (const float*)d_in[10];
    float* out = (float*)d_out;

    const size_t SEED_BYTES = (size_t)NBG * RS * SEEDSLOT * 2;   // 16 MiB each
    const size_t H0_BYTES   = (size_t)NBG * RH * H0SLOT * 2;     // 4 MiB
    char* p = (char*)d_ws;
    _Float16* seeds0 = (_Float16*)p;            p += SEED_BYTES;
    _Float16* seeds1 = (_Float16*)p;            p += SEED_BYTES;
    _Float16* h0r    = (_Float16*)p;            p += H0_BYTES;
    int*      flags  = (int*)p;

    hipMemsetAsync(flags, 0, 1024, stream);
    lstm4<<<4 * NBG, 512, 0, stream>>>(y, Wih0, Whh0, bih0, bhh0,
                                       Wih1, Whh1, bih1, bhh1, Wa, ba,
                                       seeds0, seeds1, h0r, flags, out);
}